// Round 13
// baseline (237.678 us; speedup 1.0000x reference)
//
#include <hip/hip_runtime.h>
#include <hip/hip_bf16.h>

#define LRELU(val) ((val) >= 0.0f ? (val) : 0.01f * (val))

__device__ __forceinline__ float dot4(float4 a, float4 b, float acc) {
    return fmaf(a.x, b.x, fmaf(a.y, b.y, fmaf(a.z, b.z, fmaf(a.w, b.w, acc))));
}

__device__ __forceinline__ float wdot4(const float* __restrict__ wbase, int c, int q,
                                       float4 a, float acc) {
    acc = fmaf(a.x, wbase[(4 * q + 0) * 32 + c], acc);
    acc = fmaf(a.y, wbase[(4 * q + 1) * 32 + c], acc);
    acc = fmaf(a.z, wbase[(4 * q + 2) * 32 + c], acc);
    acc = fmaf(a.w, wbase[(4 * q + 3) * 32 + c], acc);
    return acc;
}

// acc += <LDS row rp[0..31], the 8 float4 quads q0..q7>
__device__ __forceinline__ float row_wacc(const float* __restrict__ rp, float acc,
    float4 q0, float4 q1, float4 q2, float4 q3,
    float4 q4, float4 q5, float4 q6, float4 q7)
{
    acc = fmaf(rp[0],  q0.x, acc); acc = fmaf(rp[1],  q0.y, acc);
    acc = fmaf(rp[2],  q0.z, acc); acc = fmaf(rp[3],  q0.w, acc);
    acc = fmaf(rp[4],  q1.x, acc); acc = fmaf(rp[5],  q1.y, acc);
    acc = fmaf(rp[6],  q1.z, acc); acc = fmaf(rp[7],  q1.w, acc);
    acc = fmaf(rp[8],  q2.x, acc); acc = fmaf(rp[9],  q2.y, acc);
    acc = fmaf(rp[10], q2.z, acc); acc = fmaf(rp[11], q2.w, acc);
    acc = fmaf(rp[12], q3.x, acc); acc = fmaf(rp[13], q3.y, acc);
    acc = fmaf(rp[14], q3.z, acc); acc = fmaf(rp[15], q3.w, acc);
    acc = fmaf(rp[16], q4.x, acc); acc = fmaf(rp[17], q4.y, acc);
    acc = fmaf(rp[18], q4.z, acc); acc = fmaf(rp[19], q4.w, acc);
    acc = fmaf(rp[20], q5.x, acc); acc = fmaf(rp[21], q5.y, acc);
    acc = fmaf(rp[22], q5.z, acc); acc = fmaf(rp[23], q5.w, acc);
    acc = fmaf(rp[24], q6.x, acc); acc = fmaf(rp[25], q6.y, acc);
    acc = fmaf(rp[26], q6.z, acc); acc = fmaf(rp[27], q6.w, acc);
    acc = fmaf(rp[28], q7.x, acc); acc = fmaf(rp[29], q7.y, acc);
    acc = fmaf(rp[30], q7.z, acc); acc = fmaf(rp[31], q7.w, acc);
    return acc;
}

__device__ inline int lower_bound_i(const int* __restrict__ a, int n, int v) {
    int lo = 0, hi = n;
    while (lo < hi) {
        int m = (lo + hi) >> 1;
        if (a[m] < v) lo = m + 1; else hi = m;
    }
    return lo;
}

// Sortable 32-bit distance key for local candidate o = lane + 64*s, from the
// block-shared LDS tile (stride-33-padded rows, conflict-free).
__device__ __forceinline__ unsigned slot_key_lds(
    int s, int lane, int len,
    const float* __restrict__ tile, const float* __restrict__ sn, float ni,
    float4 q0, float4 q1, float4 q2, float4 q3,
    float4 q4, float4 q5, float4 q6, float4 q7)
{
    const int o = lane + 64 * s;
    const int oc = (o < len) ? o : 0;
    const float* rp = tile + oc * 33;
    const float dot = row_wacc(rp, 0.0f, q0, q1, q2, q3, q4, q5, q6, q7);
    const float d2 = (ni + sn[oc]) - 2.0f * dot;   // reference distance formula
    unsigned u = __float_as_uint(d2);
    u = (d2 < 0.0f) ? ~u : (u | 0x80000000u);      // monotone float->uint map
    return (o < len) ? u : 0xFFFFFFFFu;
}

// Membership + compaction, LOCAL indices (exact lax.top_k tie semantics).
template <int NSL>
__device__ __forceinline__ void select_compact_loc(
    unsigned k0, unsigned k1, unsigned k2, unsigned k3, unsigned k4, unsigned k5,
    unsigned T, int* __restrict__ widxW, int lane)
{
    const unsigned long long below = (1ull << lane) - 1ull;
    int m = __popcll(__ballot(k0 < T));
    if (NSL > 1) m += __popcll(__ballot(k1 < T));
    if (NSL > 2) m += __popcll(__ballot(k2 < T));
    if (NSL > 3) m += __popcll(__ballot(k3 < T));
    if (NSL > 4) m += __popcll(__ballot(k4 < T));
    if (NSL > 5) m += __popcll(__ballot(k5 < T));
    const int need = 16 - m;
    const unsigned long long e0 = __ballot(k0 == T);
    const unsigned long long e1 = (NSL > 1) ? __ballot(k1 == T) : 0ull;
    const unsigned long long e2 = (NSL > 2) ? __ballot(k2 == T) : 0ull;
    const unsigned long long e3 = (NSL > 3) ? __ballot(k3 == T) : 0ull;
    const unsigned long long e4 = (NSL > 4) ? __ballot(k4 == T) : 0ull;
    const int eq0 = __popcll(e0), eq1 = eq0 + __popcll(e1), eq2 = eq1 + __popcll(e2),
              eq3 = eq2 + __popcll(e3), eq4 = eq3 + __popcll(e4);
    const bool sel0 = (k0 < T) || ((k0 == T) && (__popcll(e0 & below) < need));
    const bool sel1 = (NSL > 1) && ((k1 < T) || ((k1 == T) && (eq0 + __popcll(e1 & below) < need)));
    const bool sel2 = (NSL > 2) && ((k2 < T) || ((k2 == T) && (eq1 + __popcll(e2 & below) < need)));
    const bool sel3 = (NSL > 3) && ((k3 < T) || ((k3 == T) && (eq2 + __popcll(e3 & below) < need)));
    const bool sel4 = (NSL > 4) && ((k4 < T) || ((k4 == T) && (eq3 + __popcll(e4 & below) < need)));
    const bool sel5 = (NSL > 5) && ((k5 < T) || ((k5 == T) && (eq4 + __popcll(__ballot(k5 == T) & below) < need)));
    const unsigned long long s0 = __ballot(sel0);
    const unsigned long long s1 = __ballot(sel1);
    const unsigned long long s2 = __ballot(sel2);
    const unsigned long long s3 = __ballot(sel3);
    const unsigned long long s4 = __ballot(sel4);
    const unsigned long long s5 = __ballot(sel5);
    const int c0 = __popcll(s0), c1 = c0 + __popcll(s1), c2 = c1 + __popcll(s2),
              c3 = c2 + __popcll(s3), c4 = c3 + __popcll(s4);
    if (lane < 16) widxW[lane] = 0;   // fallback, len<16 never in practice
    __builtin_amdgcn_wave_barrier();
    if (sel0) widxW[__popcll(s0 & below)] = lane;
    if (NSL > 1 && sel1) widxW[c0 + __popcll(s1 & below)] = lane + 64;
    if (NSL > 2 && sel2) widxW[c1 + __popcll(s2 & below)] = lane + 128;
    if (NSL > 3 && sel3) widxW[c2 + __popcll(s3 & below)] = lane + 192;
    if (NSL > 4 && sel4) widxW[c3 + __popcll(s4 & below)] = lane + 256;
    if (NSL > 5 && sel5) widxW[c4 + __popcll(s5 & below)] = lane + 320;
    __builtin_amdgcn_wave_barrier();
}

// ---------------------------------------------------------------------------
// Paired edge conv from the block-shared LDS tile. Two independent nodes per
// wave (R12's ILP win kept); distances + neighbor rows read from LDS (R12 was
// serialized on scattered-global line lookups: ~98K lines/CU ~= the 83us
// wall; the tile is staged coalesced ONCE per block for all 8 nodes).
// No block barriers inside (widx wave-private; tile read-only here).
// ---------------------------------------------------------------------------
template <int NSL>
__device__ __forceinline__ void conv_pair_lds(
    float4 ax0, float4 ax1, float4 ax2, float4 ax3,
    float4 ax4, float4 ax5, float4 ax6, float4 ax7, float niA, int lenA,
    float4 bx0, float4 bx1, float4 bx2, float4 bx3,
    float4 bx4, float4 bx5, float4 bx6, float4 bx7, float niB, int lenB,
    const float* __restrict__ tile, const float* __restrict__ sn,
    const float* __restrict__ W, const float* __restrict__ Bc,
    float4 w20, float4 w21, float4 w22, float4 w23,
    float4 w24, float4 w25, float4 w26, float4 w27,
    int* __restrict__ widxA, int* __restrict__ widxB,
    int lane, float& vOutA, float& vOutB)
{
    // Phase 1: distance keys for both nodes (LDS reads, conflict-free)
    unsigned kA0 = 0xFFFFFFFFu, kA1 = 0xFFFFFFFFu, kA2 = 0xFFFFFFFFu,
             kA3 = 0xFFFFFFFFu, kA4 = 0xFFFFFFFFu, kA5 = 0xFFFFFFFFu;
    unsigned kB0 = 0xFFFFFFFFu, kB1 = 0xFFFFFFFFu, kB2 = 0xFFFFFFFFu,
             kB3 = 0xFFFFFFFFu, kB4 = 0xFFFFFFFFu, kB5 = 0xFFFFFFFFu;
    if (lenA > 0) kA0 = slot_key_lds(0, lane, lenA, tile, sn, niA, ax0, ax1, ax2, ax3, ax4, ax5, ax6, ax7);
    if (lenB > 0) kB0 = slot_key_lds(0, lane, lenB, tile, sn, niB, bx0, bx1, bx2, bx3, bx4, bx5, bx6, bx7);
    if (NSL > 1) {
        if (lenA > 64)  kA1 = slot_key_lds(1, lane, lenA, tile, sn, niA, ax0, ax1, ax2, ax3, ax4, ax5, ax6, ax7);
        if (lenB > 64)  kB1 = slot_key_lds(1, lane, lenB, tile, sn, niB, bx0, bx1, bx2, bx3, bx4, bx5, bx6, bx7);
    }
    if (NSL > 2) {
        if (lenA > 128) kA2 = slot_key_lds(2, lane, lenA, tile, sn, niA, ax0, ax1, ax2, ax3, ax4, ax5, ax6, ax7);
        if (lenB > 128) kB2 = slot_key_lds(2, lane, lenB, tile, sn, niB, bx0, bx1, bx2, bx3, bx4, bx5, bx6, bx7);
    }
    if (NSL > 3) {
        if (lenA > 192) kA3 = slot_key_lds(3, lane, lenA, tile, sn, niA, ax0, ax1, ax2, ax3, ax4, ax5, ax6, ax7);
        if (lenB > 192) kB3 = slot_key_lds(3, lane, lenB, tile, sn, niB, bx0, bx1, bx2, bx3, bx4, bx5, bx6, bx7);
    }
    if (NSL > 4) {
        if (lenA > 256) kA4 = slot_key_lds(4, lane, lenA, tile, sn, niA, ax0, ax1, ax2, ax3, ax4, ax5, ax6, ax7);
        if (lenB > 256) kB4 = slot_key_lds(4, lane, lenB, tile, sn, niB, bx0, bx1, bx2, bx3, bx4, bx5, bx6, bx7);
    }
    if (NSL > 5) {
        if (lenA > 320) kA5 = slot_key_lds(5, lane, lenA, tile, sn, niA, ax0, ax1, ax2, ax3, ax4, ax5, ax6, ax7);
        if (lenB > 320) kB5 = slot_key_lds(5, lane, lenB, tile, sn, niB, bx0, bx1, bx2, bx3, bx4, bx5, bx6, bx7);
    }

    // Phase 2: two bisections in one loop (T = exact 16th-smallest key each).
    unsigned loA = 0u, hiA = 0xFFFFFFFFu, loB = 0u, hiB = 0xFFFFFFFFu;
#pragma unroll 1
    for (int it = 0; it < 32; ++it) {
        const unsigned mA = loA + ((hiA - loA) >> 1);
        const unsigned mB = loB + ((hiB - loB) >> 1);
        int cA = __popcll(__ballot(kA0 <= mA));
        int cB = __popcll(__ballot(kB0 <= mB));
        if (NSL > 1) { cA += __popcll(__ballot(kA1 <= mA)); cB += __popcll(__ballot(kB1 <= mB)); }
        if (NSL > 2) { cA += __popcll(__ballot(kA2 <= mA)); cB += __popcll(__ballot(kB2 <= mB)); }
        if (NSL > 3) { cA += __popcll(__ballot(kA3 <= mA)); cB += __popcll(__ballot(kB3 <= mB)); }
        if (NSL > 4) { cA += __popcll(__ballot(kA4 <= mA)); cB += __popcll(__ballot(kB4 <= mB)); }
        if (NSL > 5) { cA += __popcll(__ballot(kA5 <= mA)); cB += __popcll(__ballot(kB5 <= mB)); }
        if (loA != hiA) { if (cA >= 16) hiA = mA; else loA = mA + 1; }
        if (loB != hiB) { if (cB >= 16) hiB = mB; else loB = mB + 1; }
        if (loA == hiA && loB == hiB) break;
    }

    // Phase 3: membership + compaction per node (local indices).
    select_compact_loc<NSL>(kA0, kA1, kA2, kA3, kA4, kA5, loA, widxA, lane);
    select_compact_loc<NSL>(kB0, kB1, kB2, kB3, kB4, kB5, loB, widxB, lane);

    // cbase = Bc + xi*W1 - xi*W2   (h = cbase + nb*W2)
    const int c = lane & 31;
    float baseA = Bc[c];
    baseA = wdot4(W, c, 0, ax0, baseA); baseA = wdot4(W, c, 1, ax1, baseA);
    baseA = wdot4(W, c, 2, ax2, baseA); baseA = wdot4(W, c, 3, ax3, baseA);
    baseA = wdot4(W, c, 4, ax4, baseA); baseA = wdot4(W, c, 5, ax5, baseA);
    baseA = wdot4(W, c, 6, ax6, baseA); baseA = wdot4(W, c, 7, ax7, baseA);
    float dA = 0.0f;
    dA = dot4(ax0, w20, dA); dA = dot4(ax1, w21, dA); dA = dot4(ax2, w22, dA); dA = dot4(ax3, w23, dA);
    dA = dot4(ax4, w24, dA); dA = dot4(ax5, w25, dA); dA = dot4(ax6, w26, dA); dA = dot4(ax7, w27, dA);
    const float cbaseA = baseA - dA;

    float baseB = Bc[c];
    baseB = wdot4(W, c, 0, bx0, baseB); baseB = wdot4(W, c, 1, bx1, baseB);
    baseB = wdot4(W, c, 2, bx2, baseB); baseB = wdot4(W, c, 3, bx3, baseB);
    baseB = wdot4(W, c, 4, bx4, baseB); baseB = wdot4(W, c, 5, bx5, baseB);
    baseB = wdot4(W, c, 6, bx6, baseB); baseB = wdot4(W, c, 7, bx7, baseB);
    float dB = 0.0f;
    dB = dot4(bx0, w20, dB); dB = dot4(bx1, w21, dB); dB = dot4(bx2, w22, dB); dB = dot4(bx3, w23, dB);
    dB = dot4(bx4, w24, dB); dB = dot4(bx5, w25, dB); dB = dot4(bx6, w26, dB); dB = dot4(bx7, w27, dB);
    const float cbaseB = baseB - dB;

    // Conv rounds: neighbor rows straight from the tile (half-broadcast reads)
    const int half = lane >> 5;
    float vmA = -__builtin_huge_valf(), vmB = -__builtin_huge_valf();
#pragma unroll 1
    for (int r = 0; r < 8; ++r) {
        const int jA = widxA[2 * r + half];
        const int jB = widxB[2 * r + half];
        const float* rpA = tile + jA * 33;
        const float* rpB = tile + jB * 33;
        const float accA = row_wacc(rpA, cbaseA, w20, w21, w22, w23, w24, w25, w26, w27);
        const float accB = row_wacc(rpB, cbaseB, w20, w21, w22, w23, w24, w25, w26, w27);
        vmA = fmaxf(vmA, LRELU(accA));
        vmB = fmaxf(vmB, LRELU(accB));
    }
    vmA = fmaxf(vmA, __shfl_xor(vmA, 32));
    vmB = fmaxf(vmB, __shfl_xor(vmB, 32));
    vOutA = vmA;
    vOutB = vmB;
}

// ---------------------------------------------------------------------------
// Kernel 1: both MLP2 encoders + sq norms + group-offset tables.
// ---------------------------------------------------------------------------
__launch_bounds__(256)
__global__ void encode_kernel(const float* __restrict__ x_pfc, const float* __restrict__ x_vtx,
                              const int* __restrict__ bpfc, const int* __restrict__ bvtx,
                              const float* __restrict__ pw1, const float* __restrict__ pb1,
                              const float* __restrict__ pw2, const float* __restrict__ pb2,
                              const float* __restrict__ vw1, const float* __restrict__ vb1,
                              const float* __restrict__ vw2, const float* __restrict__ vb2,
                              float* __restrict__ pfc_enc, float* __restrict__ pfc_norm,
                              float* __restrict__ vtx_enc, float* __restrict__ vtx_norm,
                              int* __restrict__ goff_pfc, int* __restrict__ goff_vtx) {
    __shared__ float h1s[8][32];
    const int t = threadIdx.x;
    const int c = t & 31;
    const int nl = t >> 5;

    if (blockIdx.x == 0) {
        if (t < 33) goff_pfc[t] = lower_bound_i(bpfc, 8192, t);
        else if (t >= 64 && t < 97) goff_vtx[t - 64] = lower_bound_i(bvtx, 2048, t - 64);
    }

    const bool is_pfc = (blockIdx.x < 1024);
    const int node = (is_pfc ? blockIdx.x : (blockIdx.x - 1024)) * 8 + nl;
    const int din = is_pfc ? 7 : 4;
    const float* __restrict__ xin = is_pfc ? (x_pfc + node * 7) : (x_vtx + node * 4);
    const float* __restrict__ w1 = is_pfc ? pw1 : vw1;
    const float* __restrict__ b1 = is_pfc ? pb1 : vb1;
    const float* __restrict__ w2 = is_pfc ? pw2 : vw2;
    const float* __restrict__ b2 = is_pfc ? pb2 : vb2;
    float* __restrict__ enc  = is_pfc ? pfc_enc : vtx_enc;
    float* __restrict__ nrm  = is_pfc ? pfc_norm : vtx_norm;

    float h1 = b1[c];
    for (int d = 0; d < din; ++d) h1 = fmaf(xin[d], w1[d * 32 + c], h1);
    h1 = LRELU(h1);
    h1s[nl][c] = h1;
    __syncthreads();

    float h2 = b2[c];
#pragma unroll
    for (int d = 0; d < 32; ++d) h2 = fmaf(h1s[nl][d], w2[d * 32 + c], h2);
    h2 = LRELU(h2);
    enc[node * 32 + c] = h2;

    float s = h2 * h2;
#pragma unroll
    for (int m = 16; m >= 1; m >>= 1) s += __shfl_xor(s, m);
    if (c == 0) nrm[node] = s;
}

// ---------------------------------------------------------------------------
// Kernel 2: fused conv1 + conv2 with block-shared group tiles. Block = 256
// threads = 4 waves = 8 nodes (group-sorted, so the block's nodes share one
// group; the rare 2-group block loops twice, uniformly). XCD swizzle keeps a
// group's blocks on one XCD.
// ---------------------------------------------------------------------------
__launch_bounds__(256)
__global__ void fused_conv_kernel(
    const float* __restrict__ pfc_enc, const float* __restrict__ n_pfc,
    const float* __restrict__ vtx_enc, const float* __restrict__ n_vtx,
    const int* __restrict__ bpfc,
    const int* __restrict__ goff_pfc, const int* __restrict__ goff_vtx,
    const float* __restrict__ W, const float* __restrict__ Bc,
    float* __restrict__ feats2)
{
    __shared__ __align__(16) float tileP[384 * 33];   // 50688 B, pfc rows
    __shared__ __align__(16) float tileV[128 * 33];   // 16896 B, vtx rows
    __shared__ float snP[384], snV[128];
    __shared__ int widx[4][2][16];
    __shared__ __align__(16) float sRow[4][2][32];

    const int t = threadIdx.x;
    const int lane = t & 63;
    const int w = t >> 6;
    const int b = blockIdx.x;
    const int xcd = b & 7, chunk = b >> 3;
    const int nb0 = (xcd * 128 + chunk) * 8;     // block's first node
    const int iA = nb0 + w * 2, iB = iA + 1;
    const int c = lane & 31;

    // W2 column (rows 32..63, col c) into 8 float4 regs (L2-hot broadcast)
    const float4 w20 = make_float4(W[32 * 32 + c], W[33 * 32 + c], W[34 * 32 + c], W[35 * 32 + c]);
    const float4 w21 = make_float4(W[36 * 32 + c], W[37 * 32 + c], W[38 * 32 + c], W[39 * 32 + c]);
    const float4 w22 = make_float4(W[40 * 32 + c], W[41 * 32 + c], W[42 * 32 + c], W[43 * 32 + c]);
    const float4 w23 = make_float4(W[44 * 32 + c], W[45 * 32 + c], W[46 * 32 + c], W[47 * 32 + c]);
    const float4 w24 = make_float4(W[48 * 32 + c], W[49 * 32 + c], W[50 * 32 + c], W[51 * 32 + c]);
    const float4 w25 = make_float4(W[52 * 32 + c], W[53 * 32 + c], W[54 * 32 + c], W[55 * 32 + c]);
    const float4 w26 = make_float4(W[56 * 32 + c], W[57 * 32 + c], W[58 * 32 + c], W[59 * 32 + c]);
    const float4 w27 = make_float4(W[60 * 32 + c], W[61 * 32 + c], W[62 * 32 + c], W[63 * 32 + c]);

    int* widxA = &widx[w][0][0];
    int* widxB = &widx[w][1][0];

    const int gA = bpfc[iA], gB = bpfc[iB];
    const int g0 = bpfc[nb0], g1 = bpfc[nb0 + 7];

    float v2A = 0.0f, v2B = 0.0f;

#pragma unroll 1
    for (int g = g0; g <= g1; ++g) {
        const int s1 = goff_pfc[g];
        const int len1 = min(goff_pfc[g + 1] - s1, 384);
        const int s2 = goff_vtx[g];
        const int len2 = min(goff_vtx[g + 1] - s2, 128);

        // Coalesced stage of the group's rows into padded LDS tiles.
#pragma unroll 1
        for (int p = t; p < len1 * 8; p += 256) {
            const int r = p >> 3, q = p & 7;
            const float4 v = reinterpret_cast<const float4*>(pfc_enc)[(size_t)(s1 + r) * 8 + q];
            float* dp = tileP + r * 33 + q * 4;
            dp[0] = v.x; dp[1] = v.y; dp[2] = v.z; dp[3] = v.w;
        }
#pragma unroll 1
        for (int p = t; p < len2 * 8; p += 256) {
            const int r = p >> 3, q = p & 7;
            const float4 v = reinterpret_cast<const float4*>(vtx_enc)[(size_t)(s2 + r) * 8 + q];
            float* dp = tileV + r * 33 + q * 4;
            dp[0] = v.x; dp[1] = v.y; dp[2] = v.z; dp[3] = v.w;
        }
        for (int p = t; p < len1; p += 256) snP[p] = n_pfc[s1 + p];
        for (int p = t; p < len2; p += 256) snV[p] = n_vtx[s2 + p];
        __syncthreads();

        const bool actA = (gA == g), actB = (gB == g);
        if (actA || actB) {
            // ---- conv1: src = dst = pfc rows of group g ----
            const float4* xA = reinterpret_cast<const float4*>(pfc_enc + (size_t)iA * 32);
            const float4 a0 = xA[0], a1 = xA[1], a2 = xA[2], a3 = xA[3],
                         a4 = xA[4], a5 = xA[5], a6 = xA[6], a7 = xA[7];
            const float4* xB = reinterpret_cast<const float4*>(pfc_enc + (size_t)iB * 32);
            const float4 b0 = xB[0], b1 = xB[1], b2 = xB[2], b3 = xB[3],
                         b4 = xB[4], b5 = xB[5], b6 = xB[6], b7 = xB[7];
            const int lA1 = actA ? len1 : 0, lB1 = actB ? len1 : 0;

            float v1A, v1B;
            {
                const int nsl = (max(lA1, lB1) + 63) >> 6;
                if (nsl <= 2)
                    conv_pair_lds<2>(a0, a1, a2, a3, a4, a5, a6, a7, n_pfc[iA], lA1,
                                     b0, b1, b2, b3, b4, b5, b6, b7, n_pfc[iB], lB1,
                                     tileP, snP, W, Bc, w20, w21, w22, w23, w24, w25, w26, w27,
                                     widxA, widxB, lane, v1A, v1B);
                else if (nsl <= 4)
                    conv_pair_lds<4>(a0, a1, a2, a3, a4, a5, a6, a7, n_pfc[iA], lA1,
                                     b0, b1, b2, b3, b4, b5, b6, b7, n_pfc[iB], lB1,
                                     tileP, snP, W, Bc, w20, w21, w22, w23, w24, w25, w26, w27,
                                     widxA, widxB, lane, v1A, v1B);
                else
                    conv_pair_lds<6>(a0, a1, a2, a3, a4, a5, a6, a7, n_pfc[iA], lA1,
                                     b0, b1, b2, b3, b4, b5, b6, b7, n_pfc[iB], lB1,
                                     tileP, snP, W, Bc, w20, w21, w22, w23, w24, w25, w26, w27,
                                     widxA, widxB, lane, v1A, v1B);
            }

            if (lane < 32) { sRow[w][0][lane] = v1A; sRow[w][1][lane] = v1B; }
            float nfA = v1A * v1A, nfB = v1B * v1B;
#pragma unroll
            for (int m = 16; m >= 1; m >>= 1) { nfA += __shfl_xor(nfA, m); nfB += __shfl_xor(nfB, m); }
            __builtin_amdgcn_wave_barrier();

            // ---- conv2: dst = feats1 rows, src = vtx rows of group g ----
            const float4* fA = reinterpret_cast<const float4*>(&sRow[w][0][0]);
            const float4 ya0 = fA[0], ya1 = fA[1], ya2 = fA[2], ya3 = fA[3],
                         ya4 = fA[4], ya5 = fA[5], ya6 = fA[6], ya7 = fA[7];
            const float4* fB = reinterpret_cast<const float4*>(&sRow[w][1][0]);
            const float4 yb0 = fB[0], yb1 = fB[1], yb2 = fB[2], yb3 = fB[3],
                         yb4 = fB[4], yb5 = fB[5], yb6 = fB[6], yb7 = fB[7];
            const int lA2 = actA ? len2 : 0, lB2 = actB ? len2 : 0;

            float o2A, o2B;
            {
                const int nsl = (max(lA2, lB2) + 63) >> 6;
                if (nsl <= 1)
                    conv_pair_lds<1>(ya0, ya1, ya2, ya3, ya4, ya5, ya6, ya7, nfA, lA2,
                                     yb0, yb1, yb2, yb3, yb4, yb5, yb6, yb7, nfB, lB2,
                                     tileV, snV, W, Bc, w20, w21, w22, w23, w24, w25, w26, w27,
                                     widxA, widxB, lane, o2A, o2B);
                else
                    conv_pair_lds<2>(ya0, ya1, ya2, ya3, ya4, ya5, ya6, ya7, nfA, lA2,
                                     yb0, yb1, yb2, yb3, yb4, yb5, yb6, yb7, nfB, lB2,
                                     tileV, snV, W, Bc, w20, w21, w22, w23, w24, w25, w26, w27,
                                     widxA, widxB, lane, o2A, o2B);
            }
            if (actA) v2A = o2A;
            if (actB) v2B = o2B;
        }
        __syncthreads();   // tile reuse fence (uniform across the block)
    }

    if (lane < 32) {
        feats2[(size_t)iA * 32 + lane] = v2A;
        feats2[(size_t)iB * 32 + lane] = v2B;
    }
}

// ---------------------------------------------------------------------------
// Kernel 3: output MLP 32 -> 64 -> 32 -> 4 -> 1 (lrelu each) + batch copy.
// ---------------------------------------------------------------------------
__launch_bounds__(256)
__global__ void out_mlp_kernel(const float* __restrict__ f2, const int* __restrict__ bpfc,
                               const float* __restrict__ w1, const float* __restrict__ b1,
                               const float* __restrict__ w2, const float* __restrict__ b2,
                               const float* __restrict__ w3, const float* __restrict__ b3,
                               const float* __restrict__ w4, const float* __restrict__ b4,
                               float* __restrict__ dout, int N) {
    __shared__ float sW1[32 * 64], sW2[64 * 32], sW3[32 * 4];
    __shared__ float sB1[64], sB2[32], sB3[4], sW4[4], sB4[1];
    __shared__ float ex1[4][64];
    __shared__ float ex2[4][32];

    const int t = threadIdx.x;
    for (int k = t; k < 2048; k += 256) { sW1[k] = w1[k]; sW2[k] = w2[k]; }
    if (t < 128) sW3[t] = w3[t];
    if (t < 64)  sB1[t] = b1[t];
    if (t < 32)  sB2[t] = b2[t];
    if (t < 4)   { sB3[t] = b3[t]; sW4[t] = w4[t]; }
    if (t == 0)  sB4[0] = b4[0];
    __syncthreads();

    const int w = t >> 6;
    const int lane = t & 63;
    const int i = blockIdx.x * 4 + w;

    const float* fr = f2 + (size_t)i * 32;

    float h1 = sB1[lane];
#pragma unroll
    for (int d = 0; d < 32; ++d) h1 = fmaf(fr[d], sW1[d * 64 + lane], h1);
    h1 = LRELU(h1);
    ex1[w][lane] = h1;
    __syncthreads();

    const int c = lane & 31;
    float h2 = sB2[c];
#pragma unroll
    for (int d = 0; d < 64; ++d) h2 = fmaf(ex1[w][d], sW2[d * 32 + c], h2);
    h2 = LRELU(h2);
    if (lane < 32) ex2[w][c] = h2;
    __syncthreads();

    float a0 = sB3[0], a1 = sB3[1], a2 = sB3[2], a3 = sB3[3];
#pragma unroll
    for (int d = 0; d < 32; ++d) {
        float e = ex2[w][d];
        a0 = fmaf(e, sW3[d * 4 + 0], a0);
        a1 = fmaf(e, sW3[d * 4 + 1], a1);
        a2 = fmaf(e, sW3[d * 4 + 2], a2);
        a3 = fmaf(e, sW3[d * 4 + 3], a3);
    }
    a0 = LRELU(a0); a1 = LRELU(a1); a2 = LRELU(a2); a3 = LRELU(a3);
    float o = sB4[0];
    o = fmaf(a0, sW4[0], o); o = fmaf(a1, sW4[1], o);
    o = fmaf(a2, sW4[2], o); o = fmaf(a3, sW4[3], o);
    o = LRELU(o);

    if (lane == 0) dout[i] = o;                       // output 0: (8192,1)
    if (lane == 1) dout[N + i] = (float)bpfc[i];      // output 1: batch_pfc
}

// ---------------------------------------------------------------------------
extern "C" void kernel_launch(void* const* d_in, const int* in_sizes, int n_in,
                              void* d_out, int out_size, void* d_ws, size_t ws_size,
                              hipStream_t stream) {
    const float* x_pfc     = (const float*)d_in[0];
    const float* x_vtx     = (const float*)d_in[1];
    const int*   batch_pfc = (const int*)d_in[2];
    const int*   batch_vtx = (const int*)d_in[3];
    const float* pfc_w1 = (const float*)d_in[4];
    const float* pfc_b1 = (const float*)d_in[5];
    const float* pfc_w2 = (const float*)d_in[6];
    const float* pfc_b2 = (const float*)d_in[7];
    const float* vtx_w1 = (const float*)d_in[8];
    const float* vtx_b1 = (const float*)d_in[9];
    const float* vtx_w2 = (const float*)d_in[10];
    const float* vtx_b2 = (const float*)d_in[11];
    const float* conv_w = (const float*)d_in[12];
    const float* conv_b = (const float*)d_in[13];
    const float* out_w1 = (const float*)d_in[14];
    const float* out_b1 = (const float*)d_in[15];
    const float* out_w2 = (const float*)d_in[16];
    const float* out_b2 = (const float*)d_in[17];
    const float* out_w3 = (const float*)d_in[18];
    const float* out_b3 = (const float*)d_in[19];
    const float* out_w4 = (const float*)d_in[20];
    const float* out_b4 = (const float*)d_in[21];

    const int N_PFC = 8192;

    float* ws = (float*)d_ws;
    float* pfc_enc = ws;                     // 8192*32
    float* vtx_enc = ws + 262144;            // 2048*32
    float* feats2  = ws + 327680;            // 8192*32
    float* n_pfc   = ws + 589824;            // 8192
    float* n_vtx   = ws + 598016;            // 2048
    int*   goff_pfc = (int*)(ws + 600064);   // 33
    int*   goff_vtx = (int*)(ws + 600128);   // 33

    encode_kernel<<<1280, 256, 0, stream>>>(x_pfc, x_vtx, batch_pfc, batch_vtx,
                                            pfc_w1, pfc_b1, pfc_w2, pfc_b2,
                                            vtx_w1, vtx_b1, vtx_w2, vtx_b2,
                                            pfc_enc, n_pfc, vtx_enc, n_vtx,
                                            goff_pfc, goff_vtx);

    fused_conv_kernel<<<1024, 256, 0, stream>>>(pfc_enc, n_pfc, vtx_enc, n_vtx,
                                                batch_pfc, goff_pfc, goff_vtx,
                                                conv_w, conv_b, feats2);

    out_mlp_kernel<<<2048, 256, 0, stream>>>(feats2, batch_pfc,
                                             out_w1, out_b1, out_w2, out_b2,
                                             out_w3, out_b3, out_w4, out_b4,
                                             (float*)d_out, N_PFC);
}

// Round 14
// 181.161 us; speedup vs baseline: 1.3120x; 1.3120x over previous
//
#include <hip/hip_runtime.h>
#include <hip/hip_bf16.h>

#define LRELU(val) ((val) >= 0.0f ? (val) : 0.01f * (val))

__device__ __forceinline__ float dot4(float4 a, float4 b, float acc) {
    return fmaf(a.x, b.x, fmaf(a.y, b.y, fmaf(a.z, b.z, fmaf(a.w, b.w, acc))));
}

__device__ __forceinline__ float wdot4(const float* __restrict__ wbase, int c, int q,
                                       float4 a, float acc) {
    acc = fmaf(a.x, wbase[(4 * q + 0) * 32 + c], acc);
    acc = fmaf(a.y, wbase[(4 * q + 1) * 32 + c], acc);
    acc = fmaf(a.z, wbase[(4 * q + 2) * 32 + c], acc);
    acc = fmaf(a.w, wbase[(4 * q + 3) * 32 + c], acc);
    return acc;
}

__device__ inline int lower_bound_i(const int* __restrict__ a, int n, int v) {
    int lo = 0, hi = n;
    while (lo < hi) {
        int m = (lo + hi) >> 1;
        if (a[m] < v) lo = m + 1; else hi = m;
    }
    return lo;
}

// Sortable 32-bit distance key from the TRANSPOSED feature array: lane L
// reads srcT[d*N + start+L+64s] — consecutive lanes, consecutive floats
// (4 lines/instr instead of 64 — R12 was TA-line-rate-heavy at ~5.4K
// lookups/wave). The fmaf accumulation tree replicates R12's dot4 chain
// EXACTLY (per quad q: w,z,y,x with prior acc innermost) so keys are
// bit-identical -> identical neighbor selection.
__device__ __forceinline__ unsigned slot_key_T(
    int s, int lane, int start, int len, int Ns, int N,
    const float* __restrict__ srcT, const float* __restrict__ srcn, float ni,
    float4 x0, float4 x1, float4 x2, float4 x3,
    float4 x4, float4 x5, float4 x6, float4 x7)
{
    const int o = lane + 64 * s;
    const bool valid = o < len;
    const int j = valid ? (start + o) : min(start, Ns - 1);
    const float* __restrict__ T = srcT;
    float acc = 0.0f;
    acc = fmaf(T[3 * N + j],  x0.w, acc); acc = fmaf(T[2 * N + j],  x0.z, acc);
    acc = fmaf(T[1 * N + j],  x0.y, acc); acc = fmaf(T[0 * N + j],  x0.x, acc);
    acc = fmaf(T[7 * N + j],  x1.w, acc); acc = fmaf(T[6 * N + j],  x1.z, acc);
    acc = fmaf(T[5 * N + j],  x1.y, acc); acc = fmaf(T[4 * N + j],  x1.x, acc);
    acc = fmaf(T[11 * N + j], x2.w, acc); acc = fmaf(T[10 * N + j], x2.z, acc);
    acc = fmaf(T[9 * N + j],  x2.y, acc); acc = fmaf(T[8 * N + j],  x2.x, acc);
    acc = fmaf(T[15 * N + j], x3.w, acc); acc = fmaf(T[14 * N + j], x3.z, acc);
    acc = fmaf(T[13 * N + j], x3.y, acc); acc = fmaf(T[12 * N + j], x3.x, acc);
    acc = fmaf(T[19 * N + j], x4.w, acc); acc = fmaf(T[18 * N + j], x4.z, acc);
    acc = fmaf(T[17 * N + j], x4.y, acc); acc = fmaf(T[16 * N + j], x4.x, acc);
    acc = fmaf(T[23 * N + j], x5.w, acc); acc = fmaf(T[22 * N + j], x5.z, acc);
    acc = fmaf(T[21 * N + j], x5.y, acc); acc = fmaf(T[20 * N + j], x5.x, acc);
    acc = fmaf(T[27 * N + j], x6.w, acc); acc = fmaf(T[26 * N + j], x6.z, acc);
    acc = fmaf(T[25 * N + j], x6.y, acc); acc = fmaf(T[24 * N + j], x6.x, acc);
    acc = fmaf(T[31 * N + j], x7.w, acc); acc = fmaf(T[30 * N + j], x7.z, acc);
    acc = fmaf(T[29 * N + j], x7.y, acc); acc = fmaf(T[28 * N + j], x7.x, acc);
    const float d2 = (ni + srcn[j]) - 2.0f * acc;   // reference distance formula
    unsigned u = __float_as_uint(d2);
    u = (d2 < 0.0f) ? ~u : (u | 0x80000000u);       // monotone float->uint map
    return valid ? u : 0xFFFFFFFFu;
}

// Membership + compaction for one node (exact lax.top_k tie semantics).
template <int NSL>
__device__ __forceinline__ void select_compact(
    unsigned k0, unsigned k1, unsigned k2, unsigned k3, unsigned k4, unsigned k5,
    unsigned T, int start, int Ns, int* __restrict__ widxW, int lane)
{
    const unsigned long long below = (1ull << lane) - 1ull;
    int m = __popcll(__ballot(k0 < T));
    if (NSL > 1) m += __popcll(__ballot(k1 < T));
    if (NSL > 2) m += __popcll(__ballot(k2 < T));
    if (NSL > 3) m += __popcll(__ballot(k3 < T));
    if (NSL > 4) m += __popcll(__ballot(k4 < T));
    if (NSL > 5) m += __popcll(__ballot(k5 < T));
    const int need = 16 - m;
    const unsigned long long e0 = __ballot(k0 == T);
    const unsigned long long e1 = (NSL > 1) ? __ballot(k1 == T) : 0ull;
    const unsigned long long e2 = (NSL > 2) ? __ballot(k2 == T) : 0ull;
    const unsigned long long e3 = (NSL > 3) ? __ballot(k3 == T) : 0ull;
    const unsigned long long e4 = (NSL > 4) ? __ballot(k4 == T) : 0ull;
    const int eq0 = __popcll(e0), eq1 = eq0 + __popcll(e1), eq2 = eq1 + __popcll(e2),
              eq3 = eq2 + __popcll(e3), eq4 = eq3 + __popcll(e4);
    const bool sel0 = (k0 < T) || ((k0 == T) && (__popcll(e0 & below) < need));
    const bool sel1 = (NSL > 1) && ((k1 < T) || ((k1 == T) && (eq0 + __popcll(e1 & below) < need)));
    const bool sel2 = (NSL > 2) && ((k2 < T) || ((k2 == T) && (eq1 + __popcll(e2 & below) < need)));
    const bool sel3 = (NSL > 3) && ((k3 < T) || ((k3 == T) && (eq2 + __popcll(e3 & below) < need)));
    const bool sel4 = (NSL > 4) && ((k4 < T) || ((k4 == T) && (eq3 + __popcll(e4 & below) < need)));
    const bool sel5 = (NSL > 5) && ((k5 < T) || ((k5 == T) && (eq4 + __popcll(__ballot(k5 == T) & below) < need)));
    const unsigned long long s0 = __ballot(sel0);
    const unsigned long long s1 = __ballot(sel1);
    const unsigned long long s2 = __ballot(sel2);
    const unsigned long long s3 = __ballot(sel3);
    const unsigned long long s4 = __ballot(sel4);
    const unsigned long long s5 = __ballot(sel5);
    const int c0 = __popcll(s0), c1 = c0 + __popcll(s1), c2 = c1 + __popcll(s2),
              c3 = c2 + __popcll(s3), c4 = c3 + __popcll(s4);
    if (lane < 16) widxW[lane] = min(start, Ns - 1);   // fallback, len<16 never in practice
    __builtin_amdgcn_wave_barrier();
    if (sel0) widxW[__popcll(s0 & below)] = start + lane;
    if (NSL > 1 && sel1) widxW[c0 + __popcll(s1 & below)] = start + lane + 64;
    if (NSL > 2 && sel2) widxW[c1 + __popcll(s2 & below)] = start + lane + 128;
    if (NSL > 3 && sel3) widxW[c2 + __popcll(s3 & below)] = start + lane + 192;
    if (NSL > 4 && sel4) widxW[c3 + __popcll(s4 & below)] = start + lane + 256;
    if (NSL > 5 && sel5) widxW[c4 + __popcll(s5 & below)] = start + lane + 320;
    __builtin_amdgcn_wave_barrier();
}

// ---------------------------------------------------------------------------
// TWO independent nodes per wave, all phases interleaved (R12 structure —
// best measured). Distances from the TRANSPOSED array (coalesced); neighbor
// rows from the row-major array (only 16 rows). Ballot bisection + exact
// tie-order compaction. No block barriers; wave-private LDS only.
// ---------------------------------------------------------------------------
template <int NSL>
__device__ __forceinline__ void conv_pair(
    float4 ax0, float4 ax1, float4 ax2, float4 ax3,
    float4 ax4, float4 ax5, float4 ax6, float4 ax7,
    float niA, int startA, int lenA,
    float4 bx0, float4 bx1, float4 bx2, float4 bx3,
    float4 bx4, float4 bx5, float4 bx6, float4 bx7,
    float niB, int startB, int lenB,
    const float* __restrict__ srcf, const float* __restrict__ srcT,
    const float* __restrict__ srcn, int Ns,
    const float* __restrict__ W, const float* __restrict__ Bc,
    float4 w20, float4 w21, float4 w22, float4 w23,
    float4 w24, float4 w25, float4 w26, float4 w27,
    float4* __restrict__ sNbrA, float4* __restrict__ sNbrB,
    int* __restrict__ widxA, int* __restrict__ widxB,
    int lane, float& vOutA, float& vOutB)
{
    // Phase 1: distance keys for both nodes (coalesced transposed loads)
    unsigned kA0 = 0xFFFFFFFFu, kA1 = 0xFFFFFFFFu, kA2 = 0xFFFFFFFFu,
             kA3 = 0xFFFFFFFFu, kA4 = 0xFFFFFFFFu, kA5 = 0xFFFFFFFFu;
    unsigned kB0 = 0xFFFFFFFFu, kB1 = 0xFFFFFFFFu, kB2 = 0xFFFFFFFFu,
             kB3 = 0xFFFFFFFFu, kB4 = 0xFFFFFFFFu, kB5 = 0xFFFFFFFFu;
    kA0 = slot_key_T(0, lane, startA, lenA, Ns, Ns, srcT, srcn, niA, ax0, ax1, ax2, ax3, ax4, ax5, ax6, ax7);
    kB0 = slot_key_T(0, lane, startB, lenB, Ns, Ns, srcT, srcn, niB, bx0, bx1, bx2, bx3, bx4, bx5, bx6, bx7);
    if (NSL > 1) {
        if (lenA > 64)  kA1 = slot_key_T(1, lane, startA, lenA, Ns, Ns, srcT, srcn, niA, ax0, ax1, ax2, ax3, ax4, ax5, ax6, ax7);
        if (lenB > 64)  kB1 = slot_key_T(1, lane, startB, lenB, Ns, Ns, srcT, srcn, niB, bx0, bx1, bx2, bx3, bx4, bx5, bx6, bx7);
    }
    if (NSL > 2) {
        if (lenA > 128) kA2 = slot_key_T(2, lane, startA, lenA, Ns, Ns, srcT, srcn, niA, ax0, ax1, ax2, ax3, ax4, ax5, ax6, ax7);
        if (lenB > 128) kB2 = slot_key_T(2, lane, startB, lenB, Ns, Ns, srcT, srcn, niB, bx0, bx1, bx2, bx3, bx4, bx5, bx6, bx7);
    }
    if (NSL > 3) {
        if (lenA > 192) kA3 = slot_key_T(3, lane, startA, lenA, Ns, Ns, srcT, srcn, niA, ax0, ax1, ax2, ax3, ax4, ax5, ax6, ax7);
        if (lenB > 192) kB3 = slot_key_T(3, lane, startB, lenB, Ns, Ns, srcT, srcn, niB, bx0, bx1, bx2, bx3, bx4, bx5, bx6, bx7);
    }
    if (NSL > 4) {
        if (lenA > 256) kA4 = slot_key_T(4, lane, startA, lenA, Ns, Ns, srcT, srcn, niA, ax0, ax1, ax2, ax3, ax4, ax5, ax6, ax7);
        if (lenB > 256) kB4 = slot_key_T(4, lane, startB, lenB, Ns, Ns, srcT, srcn, niB, bx0, bx1, bx2, bx3, bx4, bx5, bx6, bx7);
    }
    if (NSL > 5) {
        if (lenA > 320) kA5 = slot_key_T(5, lane, startA, lenA, Ns, Ns, srcT, srcn, niA, ax0, ax1, ax2, ax3, ax4, ax5, ax6, ax7);
        if (lenB > 320) kB5 = slot_key_T(5, lane, startB, lenB, Ns, Ns, srcT, srcn, niB, bx0, bx1, bx2, bx3, bx4, bx5, bx6, bx7);
    }

    // Phase 2: two bisections in one loop (independent scalar states).
    unsigned loA = 0u, hiA = 0xFFFFFFFFu, loB = 0u, hiB = 0xFFFFFFFFu;
#pragma unroll 1
    for (int it = 0; it < 32; ++it) {
        const unsigned mA = loA + ((hiA - loA) >> 1);
        const unsigned mB = loB + ((hiB - loB) >> 1);
        int cA = __popcll(__ballot(kA0 <= mA));
        int cB = __popcll(__ballot(kB0 <= mB));
        if (NSL > 1) { cA += __popcll(__ballot(kA1 <= mA)); cB += __popcll(__ballot(kB1 <= mB)); }
        if (NSL > 2) { cA += __popcll(__ballot(kA2 <= mA)); cB += __popcll(__ballot(kB2 <= mB)); }
        if (NSL > 3) { cA += __popcll(__ballot(kA3 <= mA)); cB += __popcll(__ballot(kB3 <= mB)); }
        if (NSL > 4) { cA += __popcll(__ballot(kA4 <= mA)); cB += __popcll(__ballot(kB4 <= mB)); }
        if (NSL > 5) { cA += __popcll(__ballot(kA5 <= mA)); cB += __popcll(__ballot(kB5 <= mB)); }
        if (loA != hiA) { if (cA >= 16) hiA = mA; else loA = mA + 1; }
        if (loB != hiB) { if (cB >= 16) hiB = mB; else loB = mB + 1; }
        if (loA == hiA && loB == hiB) break;
    }

    // Phase 3: membership + compaction per node.
    select_compact<NSL>(kA0, kA1, kA2, kA3, kA4, kA5, loA, startA, Ns, widxA, lane);
    select_compact<NSL>(kB0, kB1, kB2, kB3, kB4, kB5, loB, startB, Ns, widxB, lane);

    // Stage 16 neighbor rows per node (row-major; 4 independent loads/lane),
    // overlapping with both base computations.
    const int c = lane & 31;
    const int n0 = lane >> 3, qq = lane & 7;
    const int n1 = n0 + 8;
    int jA0 = widxA[n0]; jA0 = ((unsigned)jA0 < (unsigned)Ns) ? jA0 : 0;
    int jA1 = widxA[n1]; jA1 = ((unsigned)jA1 < (unsigned)Ns) ? jA1 : 0;
    int jB0 = widxB[n0]; jB0 = ((unsigned)jB0 < (unsigned)Ns) ? jB0 : 0;
    int jB1 = widxB[n1]; jB1 = ((unsigned)jB1 < (unsigned)Ns) ? jB1 : 0;
    const float4* S = reinterpret_cast<const float4*>(srcf);
    const float4 rA0 = S[(size_t)jA0 * 8 + qq];
    const float4 rA1 = S[(size_t)jA1 * 8 + qq];
    const float4 rB0 = S[(size_t)jB0 * 8 + qq];
    const float4 rB1 = S[(size_t)jB1 * 8 + qq];

    float baseA = Bc[c];
    baseA = wdot4(W, c, 0, ax0, baseA); baseA = wdot4(W, c, 1, ax1, baseA);
    baseA = wdot4(W, c, 2, ax2, baseA); baseA = wdot4(W, c, 3, ax3, baseA);
    baseA = wdot4(W, c, 4, ax4, baseA); baseA = wdot4(W, c, 5, ax5, baseA);
    baseA = wdot4(W, c, 6, ax6, baseA); baseA = wdot4(W, c, 7, ax7, baseA);
    float dA = 0.0f;
    dA = dot4(ax0, w20, dA); dA = dot4(ax1, w21, dA); dA = dot4(ax2, w22, dA); dA = dot4(ax3, w23, dA);
    dA = dot4(ax4, w24, dA); dA = dot4(ax5, w25, dA); dA = dot4(ax6, w26, dA); dA = dot4(ax7, w27, dA);
    const float cbaseA = baseA - dA;

    float baseB = Bc[c];
    baseB = wdot4(W, c, 0, bx0, baseB); baseB = wdot4(W, c, 1, bx1, baseB);
    baseB = wdot4(W, c, 2, bx2, baseB); baseB = wdot4(W, c, 3, bx3, baseB);
    baseB = wdot4(W, c, 4, bx4, baseB); baseB = wdot4(W, c, 5, bx5, baseB);
    baseB = wdot4(W, c, 6, bx6, baseB); baseB = wdot4(W, c, 7, bx7, baseB);
    float dB = 0.0f;
    dB = dot4(bx0, w20, dB); dB = dot4(bx1, w21, dB); dB = dot4(bx2, w22, dB); dB = dot4(bx3, w23, dB);
    dB = dot4(bx4, w24, dB); dB = dot4(bx5, w25, dB); dB = dot4(bx6, w26, dB); dB = dot4(bx7, w27, dB);
    const float cbaseB = baseB - dB;

    sNbrA[n0 * 8 + qq] = rA0;
    sNbrA[n1 * 8 + qq] = rA1;
    sNbrB[n0 * 8 + qq] = rB0;
    sNbrB[n1 * 8 + qq] = rB1;
    __builtin_amdgcn_wave_barrier();

    // Conv rounds, both nodes interleaved; 2 neighbors/round (half-wave each)
    const int half = lane >> 5;
    float vmA = -__builtin_huge_valf(), vmB = -__builtin_huge_valf();
#pragma unroll 1
    for (int r = 0; r < 8; ++r) {
        const float4* nA = sNbrA + (2 * r + half) * 8;
        const float4* nB = sNbrB + (2 * r + half) * 8;
        float accA = cbaseA, accB = cbaseB;
        accA = dot4(nA[0], w20, accA); accB = dot4(nB[0], w20, accB);
        accA = dot4(nA[1], w21, accA); accB = dot4(nB[1], w21, accB);
        accA = dot4(nA[2], w22, accA); accB = dot4(nB[2], w22, accB);
        accA = dot4(nA[3], w23, accA); accB = dot4(nB[3], w23, accB);
        accA = dot4(nA[4], w24, accA); accB = dot4(nB[4], w24, accB);
        accA = dot4(nA[5], w25, accA); accB = dot4(nB[5], w25, accB);
        accA = dot4(nA[6], w26, accA); accB = dot4(nB[6], w26, accB);
        accA = dot4(nA[7], w27, accA); accB = dot4(nB[7], w27, accB);
        vmA = fmaxf(vmA, LRELU(accA));
        vmB = fmaxf(vmB, LRELU(accB));
    }
    vmA = fmaxf(vmA, __shfl_xor(vmA, 32));
    vmB = fmaxf(vmB, __shfl_xor(vmB, 32));
    vOutA = vmA;
    vOutB = vmB;
}

// ---------------------------------------------------------------------------
// Kernel 1: both MLP2 encoders + sq norms + group-offset tables + transposed
// feature copies (encT[d][n], for coalesced distance loads in the conv).
// ---------------------------------------------------------------------------
__launch_bounds__(256)
__global__ void encode_kernel(const float* __restrict__ x_pfc, const float* __restrict__ x_vtx,
                              const int* __restrict__ bpfc, const int* __restrict__ bvtx,
                              const float* __restrict__ pw1, const float* __restrict__ pb1,
                              const float* __restrict__ pw2, const float* __restrict__ pb2,
                              const float* __restrict__ vw1, const float* __restrict__ vb1,
                              const float* __restrict__ vw2, const float* __restrict__ vb2,
                              float* __restrict__ pfc_enc, float* __restrict__ pfc_norm,
                              float* __restrict__ vtx_enc, float* __restrict__ vtx_norm,
                              float* __restrict__ pfc_encT, float* __restrict__ vtx_encT,
                              int* __restrict__ goff_pfc, int* __restrict__ goff_vtx) {
    __shared__ float h1s[8][32];
    const int t = threadIdx.x;
    const int c = t & 31;
    const int nl = t >> 5;

    if (blockIdx.x == 0) {
        if (t < 33) goff_pfc[t] = lower_bound_i(bpfc, 8192, t);
        else if (t >= 64 && t < 97) goff_vtx[t - 64] = lower_bound_i(bvtx, 2048, t - 64);
    }

    const bool is_pfc = (blockIdx.x < 1024);
    const int node = (is_pfc ? blockIdx.x : (blockIdx.x - 1024)) * 8 + nl;
    const int din = is_pfc ? 7 : 4;
    const int Nn = is_pfc ? 8192 : 2048;
    const float* __restrict__ xin = is_pfc ? (x_pfc + node * 7) : (x_vtx + node * 4);
    const float* __restrict__ w1 = is_pfc ? pw1 : vw1;
    const float* __restrict__ b1 = is_pfc ? pb1 : vb1;
    const float* __restrict__ w2 = is_pfc ? pw2 : vw2;
    const float* __restrict__ b2 = is_pfc ? pb2 : vb2;
    float* __restrict__ enc  = is_pfc ? pfc_enc : vtx_enc;
    float* __restrict__ encT = is_pfc ? pfc_encT : vtx_encT;
    float* __restrict__ nrm  = is_pfc ? pfc_norm : vtx_norm;

    float h1 = b1[c];
    for (int d = 0; d < din; ++d) h1 = fmaf(xin[d], w1[d * 32 + c], h1);
    h1 = LRELU(h1);
    h1s[nl][c] = h1;
    __syncthreads();

    float h2 = b2[c];
#pragma unroll
    for (int d = 0; d < 32; ++d) h2 = fmaf(h1s[nl][d], w2[d * 32 + c], h2);
    h2 = LRELU(h2);
    enc[node * 32 + c] = h2;
    encT[(size_t)c * Nn + node] = h2;

    float s = h2 * h2;
#pragma unroll
    for (int m = 16; m >= 1; m >>= 1) s += __shfl_xor(s, m);
    if (c == 0) nrm[node] = s;
}

// ---------------------------------------------------------------------------
// Kernel 2: fused conv1 + conv2, TWO nodes per wave, 128-thr blocks, zero
// block barriers. XCD swizzle keeps a group's candidate rows in one XCD L2.
// ---------------------------------------------------------------------------
__launch_bounds__(128)
__global__ void fused_conv_kernel(
    const float* __restrict__ pfc_enc, const float* __restrict__ pfc_encT,
    const float* __restrict__ n_pfc,
    const float* __restrict__ vtx_enc, const float* __restrict__ vtx_encT,
    const float* __restrict__ n_vtx,
    const int* __restrict__ bpfc,
    const int* __restrict__ goff_pfc, const int* __restrict__ goff_vtx,
    const float* __restrict__ W, const float* __restrict__ Bc,
    float* __restrict__ feats2)
{
    __shared__ __align__(16) float4 sNbr[2][2][128];   // [wave][node]
    __shared__ int widx[2][2][16];
    __shared__ __align__(16) float sRow[2][2][32];

    const int t = threadIdx.x;
    const int lane = t & 63;
    const int w = t >> 6;
    const int b = blockIdx.x;              // 2048 blocks x 4 nodes
    const int xcd = b & 7, chunk = b >> 3;
    const int iA = xcd * 1024 + chunk * 4 + w * 2;
    const int iB = iA + 1;
    const int c = lane & 31;

    // Hoisted W2 column (rows 32..63, col c) — shared by both convs.
    const float4 w20 = make_float4(W[32 * 32 + c], W[33 * 32 + c], W[34 * 32 + c], W[35 * 32 + c]);
    const float4 w21 = make_float4(W[36 * 32 + c], W[37 * 32 + c], W[38 * 32 + c], W[39 * 32 + c]);
    const float4 w22 = make_float4(W[40 * 32 + c], W[41 * 32 + c], W[42 * 32 + c], W[43 * 32 + c]);
    const float4 w23 = make_float4(W[44 * 32 + c], W[45 * 32 + c], W[46 * 32 + c], W[47 * 32 + c]);
    const float4 w24 = make_float4(W[48 * 32 + c], W[49 * 32 + c], W[50 * 32 + c], W[51 * 32 + c]);
    const float4 w25 = make_float4(W[52 * 32 + c], W[53 * 32 + c], W[54 * 32 + c], W[55 * 32 + c]);
    const float4 w26 = make_float4(W[56 * 32 + c], W[57 * 32 + c], W[58 * 32 + c], W[59 * 32 + c]);
    const float4 w27 = make_float4(W[60 * 32 + c], W[61 * 32 + c], W[62 * 32 + c], W[63 * 32 + c]);

    float4* sNbrA = &sNbr[w][0][0];
    float4* sNbrB = &sNbr[w][1][0];
    int* widxA = &widx[w][0][0];
    int* widxB = &widx[w][1][0];

    const int gA = bpfc[iA], gB = bpfc[iB];

    // ---- conv1: src = dst = pfc (group ~256±16 -> nsl 4 or 5) ----
    const float4* xA = reinterpret_cast<const float4*>(pfc_enc + (size_t)iA * 32);
    const float4 a0 = xA[0], a1 = xA[1], a2 = xA[2], a3 = xA[3],
                 a4 = xA[4], a5 = xA[5], a6 = xA[6], a7 = xA[7];
    const float4* xB = reinterpret_cast<const float4*>(pfc_enc + (size_t)iB * 32);
    const float4 b0 = xB[0], b1 = xB[1], b2 = xB[2], b3 = xB[3],
                 b4 = xB[4], b5 = xB[5], b6 = xB[6], b7 = xB[7];
    const float niA = n_pfc[iA], niB = n_pfc[iB];
    const int s1A = goff_pfc[gA], len1A = min(goff_pfc[gA + 1] - s1A, 384);
    const int s1B = goff_pfc[gB], len1B = min(goff_pfc[gB + 1] - s1B, 384);

    float v1A, v1B;
    {
        const int nsl = (max(len1A, len1B) + 63) >> 6;
        if (nsl <= 4)
            conv_pair<4>(a0, a1, a2, a3, a4, a5, a6, a7, niA, s1A, len1A,
                         b0, b1, b2, b3, b4, b5, b6, b7, niB, s1B, len1B,
                         pfc_enc, pfc_encT, n_pfc, 8192, W, Bc,
                         w20, w21, w22, w23, w24, w25, w26, w27,
                         sNbrA, sNbrB, widxA, widxB, lane, v1A, v1B);
        else
            conv_pair<6>(a0, a1, a2, a3, a4, a5, a6, a7, niA, s1A, len1A,
                         b0, b1, b2, b3, b4, b5, b6, b7, niB, s1B, len1B,
                         pfc_enc, pfc_encT, n_pfc, 8192, W, Bc,
                         w20, w21, w22, w23, w24, w25, w26, w27,
                         sNbrA, sNbrB, widxA, widxB, lane, v1A, v1B);
    }

    if (lane < 32) { sRow[w][0][lane] = v1A; sRow[w][1][lane] = v1B; }
    float nfA = v1A * v1A, nfB = v1B * v1B;
#pragma unroll
    for (int m = 16; m >= 1; m >>= 1) { nfA += __shfl_xor(nfA, m); nfB += __shfl_xor(nfB, m); }
    __builtin_amdgcn_wave_barrier();

    // ---- conv2: dst = feats1 rows (wave-private LDS), src = vtx (~64±8) ----
    const float4* fA = reinterpret_cast<const float4*>(&sRow[w][0][0]);
    const float4 ya0 = fA[0], ya1 = fA[1], ya2 = fA[2], ya3 = fA[3],
                 ya4 = fA[4], ya5 = fA[5], ya6 = fA[6], ya7 = fA[7];
    const float4* fB = reinterpret_cast<const float4*>(&sRow[w][1][0]);
    const float4 yb0 = fB[0], yb1 = fB[1], yb2 = fB[2], yb3 = fB[3],
                 yb4 = fB[4], yb5 = fB[5], yb6 = fB[6], yb7 = fB[7];
    const int s2A = goff_vtx[gA], len2A = min(goff_vtx[gA + 1] - s2A, 128);
    const int s2B = goff_vtx[gB], len2B = min(goff_vtx[gB + 1] - s2B, 128);

    float v2A, v2B;
    conv_pair<2>(ya0, ya1, ya2, ya3, ya4, ya5, ya6, ya7, nfA, s2A, len2A,
                 yb0, yb1, yb2, yb3, yb4, yb5, yb6, yb7, nfB, s2B, len2B,
                 vtx_enc, vtx_encT, n_vtx, 2048, W, Bc,
                 w20, w21, w22, w23, w24, w25, w26, w27,
                 sNbrA, sNbrB, widxA, widxB, lane, v2A, v2B);

    if (lane < 32) {
        feats2[(size_t)iA * 32 + lane] = v2A;
        feats2[(size_t)iB * 32 + lane] = v2B;
    }
}

// ---------------------------------------------------------------------------
// Kernel 3: output MLP 32 -> 64 -> 32 -> 4 -> 1 (lrelu each) + batch copy.
// ---------------------------------------------------------------------------
__launch_bounds__(256)
__global__ void out_mlp_kernel(const float* __restrict__ f2, const int* __restrict__ bpfc,
                               const float* __restrict__ w1, const float* __restrict__ b1,
                               const float* __restrict__ w2, const float* __restrict__ b2,
                               const float* __restrict__ w3, const float* __restrict__ b3,
                               const float* __restrict__ w4, const float* __restrict__ b4,
                               float* __restrict__ dout, int N) {
    __shared__ float sW1[32 * 64], sW2[64 * 32], sW3[32 * 4];
    __shared__ float sB1[64], sB2[32], sB3[4], sW4[4], sB4[1];
    __shared__ float ex1[4][64];
    __shared__ float ex2[4][32];

    const int t = threadIdx.x;
    for (int k = t; k < 2048; k += 256) { sW1[k] = w1[k]; sW2[k] = w2[k]; }
    if (t < 128) sW3[t] = w3[t];
    if (t < 64)  sB1[t] = b1[t];
    if (t < 32)  sB2[t] = b2[t];
    if (t < 4)   { sB3[t] = b3[t]; sW4[t] = w4[t]; }
    if (t == 0)  sB4[0] = b4[0];
    __syncthreads();

    const int w = t >> 6;
    const int lane = t & 63;
    const int i = blockIdx.x * 4 + w;

    const float* fr = f2 + (size_t)i * 32;

    float h1 = sB1[lane];
#pragma unroll
    for (int d = 0; d < 32; ++d) h1 = fmaf(fr[d], sW1[d * 64 + lane], h1);
    h1 = LRELU(h1);
    ex1[w][lane] = h1;
    __syncthreads();

    const int c = lane & 31;
    float h2 = sB2[c];
#pragma unroll
    for (int d = 0; d < 64; ++d) h2 = fmaf(ex1[w][d], sW2[d * 32 + c], h2);
    h2 = LRELU(h2);
    if (lane < 32) ex2[w][c] = h2;
    __syncthreads();

    float a0 = sB3[0], a1 = sB3[1], a2 = sB3[2], a3 = sB3[3];
#pragma unroll
    for (int d = 0; d < 32; ++d) {
        float e = ex2[w][d];
        a0 = fmaf(e, sW3[d * 4 + 0], a0);
        a1 = fmaf(e, sW3[d * 4 + 1], a1);
        a2 = fmaf(e, sW3[d * 4 + 2], a2);
        a3 = fmaf(e, sW3[d * 4 + 3], a3);
    }
    a0 = LRELU(a0); a1 = LRELU(a1); a2 = LRELU(a2); a3 = LRELU(a3);
    float o = sB4[0];
    o = fmaf(a0, sW4[0], o); o = fmaf(a1, sW4[1], o);
    o = fmaf(a2, sW4[2], o); o = fmaf(a3, sW4[3], o);
    o = LRELU(o);

    if (lane == 0) dout[i] = o;                       // output 0: (8192,1)
    if (lane == 1) dout[N + i] = (float)bpfc[i];      // output 1: batch_pfc
}

// ---------------------------------------------------------------------------
extern "C" void kernel_launch(void* const* d_in, const int* in_sizes, int n_in,
                              void* d_out, int out_size, void* d_ws, size_t ws_size,
                              hipStream_t stream) {
    const float* x_pfc     = (const float*)d_in[0];
    const float* x_vtx     = (const float*)d_in[1];
    const int*   batch_pfc = (const int*)d_in[2];
    const int*   batch_vtx = (const int*)d_in[3];
    const float* pfc_w1 = (const float*)d_in[4];
    const float* pfc_b1 = (const float*)d_in[5];
    const float* pfc_w2 = (const float*)d_in[6];
    const float* pfc_b2 = (const float*)d_in[7];
    const float* vtx_w1 = (const float*)d_in[8];
    const float* vtx_b1 = (const float*)d_in[9];
    const float* vtx_w2 = (const float*)d_in[10];
    const float* vtx_b2 = (const float*)d_in[11];
    const float* conv_w = (const float*)d_in[12];
    const float* conv_b = (const float*)d_in[13];
    const float* out_w1 = (const float*)d_in[14];
    const float* out_b1 = (const float*)d_in[15];
    const float* out_w2 = (const float*)d_in[16];
    const float* out_b2 = (const float*)d_in[17];
    const float* out_w3 = (const float*)d_in[18];
    const float* out_b3 = (const float*)d_in[19];
    const float* out_w4 = (const float*)d_in[20];
    const float* out_b4 = (const float*)d_in[21];

    const int N_PFC = 8192;

    float* ws = (float*)d_ws;
    float* pfc_enc  = ws;                     // 8192*32
    float* vtx_enc  = ws + 262144;            // 2048*32
    float* feats2   = ws + 327680;            // 8192*32
    float* n_pfc    = ws + 589824;            // 8192
    float* n_vtx    = ws + 598016;            // 2048
    int*   goff_pfc = (int*)(ws + 600064);    // 33 (+pad)
    int*   goff_vtx = (int*)(ws + 600128);    // 33 (+pad)
    float* pfc_encT = ws + 600192;            // 32*8192
    float* vtx_encT = ws + 862336;            // 32*2048  (total 927872 floats)

    encode_kernel<<<1280, 256, 0, stream>>>(x_pfc, x_vtx, batch_pfc, batch_vtx,
                                            pfc_w1, pfc_b1, pfc_w2, pfc_b2,
                                            vtx_w1, vtx_b1, vtx_w2, vtx_b2,
                                            pfc_enc, n_pfc, vtx_enc, n_vtx,
                                            pfc_encT, vtx_encT,
                                            goff_pfc, goff_vtx);

    fused_conv_kernel<<<2048, 128, 0, stream>>>(pfc_enc, pfc_encT, n_pfc,
                                                vtx_enc, vtx_encT, n_vtx,
                                                batch_pfc, goff_pfc, goff_vtx,
                                                conv_w, conv_b, feats2);

    out_mlp_kernel<<<2048, 256, 0, stream>>>(feats2, batch_pfc,
                                             out_w1, out_b1, out_w2, out_b2,
                                             out_w3, out_b3, out_w4, out_b4,
                                             (float*)d_out, N_PFC);
}

// Round 15
// 179.320 us; speedup vs baseline: 1.3254x; 1.0103x over previous
//
#include <hip/hip_runtime.h>
#include <hip/hip_bf16.h>

#define LRELU(val) ((val) >= 0.0f ? (val) : 0.01f * (val))

__device__ __forceinline__ float dot4(float4 a, float4 b, float acc) {
    return fmaf(a.x, b.x, fmaf(a.y, b.y, fmaf(a.z, b.z, fmaf(a.w, b.w, acc))));
}

__device__ __forceinline__ float wdot4(const float* __restrict__ wbase, int c, int q,
                                       float4 a, float acc) {
    acc = fmaf(a.x, wbase[(4 * q + 0) * 32 + c], acc);
    acc = fmaf(a.y, wbase[(4 * q + 1) * 32 + c], acc);
    acc = fmaf(a.z, wbase[(4 * q + 2) * 32 + c], acc);
    acc = fmaf(a.w, wbase[(4 * q + 3) * 32 + c], acc);
    return acc;
}

__device__ inline int lower_bound_i(const int* __restrict__ a, int n, int v) {
    int lo = 0, hi = n;
    while (lo < hi) {
        int m = (lo + hi) >> 1;
        if (a[m] < v) lo = m + 1; else hi = m;
    }
    return lo;
}

// Sortable 32-bit distance key from the TRANSPOSED feature array (coalesced:
// lane L reads srcT[d*N + start+L+64s]). fmaf tree replicates the row-major
// dot4 chain EXACTLY so keys are bit-identical -> identical selection.
__device__ __forceinline__ unsigned slot_key_T(
    int s, int lane, int start, int len, int Ns, int N,
    const float* __restrict__ srcT, const float* __restrict__ srcn, float ni,
    float4 x0, float4 x1, float4 x2, float4 x3,
    float4 x4, float4 x5, float4 x6, float4 x7)
{
    const int o = lane + 64 * s;
    const bool valid = o < len;
    const int j = valid ? (start + o) : min(start, Ns - 1);
    const float* __restrict__ T = srcT;
    float acc = 0.0f;
    acc = fmaf(T[3 * N + j],  x0.w, acc); acc = fmaf(T[2 * N + j],  x0.z, acc);
    acc = fmaf(T[1 * N + j],  x0.y, acc); acc = fmaf(T[0 * N + j],  x0.x, acc);
    acc = fmaf(T[7 * N + j],  x1.w, acc); acc = fmaf(T[6 * N + j],  x1.z, acc);
    acc = fmaf(T[5 * N + j],  x1.y, acc); acc = fmaf(T[4 * N + j],  x1.x, acc);
    acc = fmaf(T[11 * N + j], x2.w, acc); acc = fmaf(T[10 * N + j], x2.z, acc);
    acc = fmaf(T[9 * N + j],  x2.y, acc); acc = fmaf(T[8 * N + j],  x2.x, acc);
    acc = fmaf(T[15 * N + j], x3.w, acc); acc = fmaf(T[14 * N + j], x3.z, acc);
    acc = fmaf(T[13 * N + j], x3.y, acc); acc = fmaf(T[12 * N + j], x3.x, acc);
    acc = fmaf(T[19 * N + j], x4.w, acc); acc = fmaf(T[18 * N + j], x4.z, acc);
    acc = fmaf(T[17 * N + j], x4.y, acc); acc = fmaf(T[16 * N + j], x4.x, acc);
    acc = fmaf(T[23 * N + j], x5.w, acc); acc = fmaf(T[22 * N + j], x5.z, acc);
    acc = fmaf(T[21 * N + j], x5.y, acc); acc = fmaf(T[20 * N + j], x5.x, acc);
    acc = fmaf(T[27 * N + j], x6.w, acc); acc = fmaf(T[26 * N + j], x6.z, acc);
    acc = fmaf(T[25 * N + j], x6.y, acc); acc = fmaf(T[24 * N + j], x6.x, acc);
    acc = fmaf(T[31 * N + j], x7.w, acc); acc = fmaf(T[30 * N + j], x7.z, acc);
    acc = fmaf(T[29 * N + j], x7.y, acc); acc = fmaf(T[28 * N + j], x7.x, acc);
    const float d2 = (ni + srcn[j]) - 2.0f * acc;   // reference distance formula
    unsigned u = __float_as_uint(d2);
    u = (d2 < 0.0f) ? ~u : (u | 0x80000000u);       // monotone float->uint map
    return valid ? u : 0xFFFFFFFFu;
}

// Membership + compaction for one node (exact lax.top_k tie semantics).
template <int NSL>
__device__ __forceinline__ void select_compact(
    unsigned k0, unsigned k1, unsigned k2, unsigned k3, unsigned k4, unsigned k5,
    unsigned T, int start, int Ns, int* __restrict__ widxW, int lane)
{
    const unsigned long long below = (1ull << lane) - 1ull;
    int m = __popcll(__ballot(k0 < T));
    if (NSL > 1) m += __popcll(__ballot(k1 < T));
    if (NSL > 2) m += __popcll(__ballot(k2 < T));
    if (NSL > 3) m += __popcll(__ballot(k3 < T));
    if (NSL > 4) m += __popcll(__ballot(k4 < T));
    if (NSL > 5) m += __popcll(__ballot(k5 < T));
    const int need = 16 - m;
    const unsigned long long e0 = __ballot(k0 == T);
    const unsigned long long e1 = (NSL > 1) ? __ballot(k1 == T) : 0ull;
    const unsigned long long e2 = (NSL > 2) ? __ballot(k2 == T) : 0ull;
    const unsigned long long e3 = (NSL > 3) ? __ballot(k3 == T) : 0ull;
    const unsigned long long e4 = (NSL > 4) ? __ballot(k4 == T) : 0ull;
    const int eq0 = __popcll(e0), eq1 = eq0 + __popcll(e1), eq2 = eq1 + __popcll(e2),
              eq3 = eq2 + __popcll(e3), eq4 = eq3 + __popcll(e4);
    const bool sel0 = (k0 < T) || ((k0 == T) && (__popcll(e0 & below) < need));
    const bool sel1 = (NSL > 1) && ((k1 < T) || ((k1 == T) && (eq0 + __popcll(e1 & below) < need)));
    const bool sel2 = (NSL > 2) && ((k2 < T) || ((k2 == T) && (eq1 + __popcll(e2 & below) < need)));
    const bool sel3 = (NSL > 3) && ((k3 < T) || ((k3 == T) && (eq2 + __popcll(e3 & below) < need)));
    const bool sel4 = (NSL > 4) && ((k4 < T) || ((k4 == T) && (eq3 + __popcll(e4 & below) < need)));
    const bool sel5 = (NSL > 5) && ((k5 < T) || ((k5 == T) && (eq4 + __popcll(__ballot(k5 == T) & below) < need)));
    const unsigned long long s0 = __ballot(sel0);
    const unsigned long long s1 = __ballot(sel1);
    const unsigned long long s2 = __ballot(sel2);
    const unsigned long long s3 = __ballot(sel3);
    const unsigned long long s4 = __ballot(sel4);
    const unsigned long long s5 = __ballot(sel5);
    const int c0 = __popcll(s0), c1 = c0 + __popcll(s1), c2 = c1 + __popcll(s2),
              c3 = c2 + __popcll(s3), c4 = c3 + __popcll(s4);
    if (lane < 16) widxW[lane] = min(start, Ns - 1);   // fallback, len<16 never in practice
    __builtin_amdgcn_wave_barrier();
    if (sel0) widxW[__popcll(s0 & below)] = start + lane;
    if (NSL > 1 && sel1) widxW[c0 + __popcll(s1 & below)] = start + lane + 64;
    if (NSL > 2 && sel2) widxW[c1 + __popcll(s2 & below)] = start + lane + 128;
    if (NSL > 3 && sel3) widxW[c2 + __popcll(s3 & below)] = start + lane + 192;
    if (NSL > 4 && sel4) widxW[c3 + __popcll(s4 & below)] = start + lane + 256;
    if (NSL > 5 && sel5) widxW[c4 + __popcll(s5 & below)] = start + lane + 320;
    __builtin_amdgcn_wave_barrier();
}

// ---------------------------------------------------------------------------
// TWO independent nodes per wave, all phases interleaved. Distances from the
// transposed array (coalesced); neighbor rows from the row-major array.
// Ballot bisection + exact tie-order compaction. No block barriers.
// ---------------------------------------------------------------------------
template <int NSL>
__device__ __forceinline__ void conv_pair(
    float4 ax0, float4 ax1, float4 ax2, float4 ax3,
    float4 ax4, float4 ax5, float4 ax6, float4 ax7,
    float niA, int startA, int lenA,
    float4 bx0, float4 bx1, float4 bx2, float4 bx3,
    float4 bx4, float4 bx5, float4 bx6, float4 bx7,
    float niB, int startB, int lenB,
    const float* __restrict__ srcf, const float* __restrict__ srcT,
    const float* __restrict__ srcn, int Ns,
    const float* __restrict__ W, const float* __restrict__ Bc,
    float4 w20, float4 w21, float4 w22, float4 w23,
    float4 w24, float4 w25, float4 w26, float4 w27,
    float4* __restrict__ sNbrA, float4* __restrict__ sNbrB,
    int* __restrict__ widxA, int* __restrict__ widxB,
    int lane, float& vOutA, float& vOutB)
{
    unsigned kA0 = 0xFFFFFFFFu, kA1 = 0xFFFFFFFFu, kA2 = 0xFFFFFFFFu,
             kA3 = 0xFFFFFFFFu, kA4 = 0xFFFFFFFFu, kA5 = 0xFFFFFFFFu;
    unsigned kB0 = 0xFFFFFFFFu, kB1 = 0xFFFFFFFFu, kB2 = 0xFFFFFFFFu,
             kB3 = 0xFFFFFFFFu, kB4 = 0xFFFFFFFFu, kB5 = 0xFFFFFFFFu;
    kA0 = slot_key_T(0, lane, startA, lenA, Ns, Ns, srcT, srcn, niA, ax0, ax1, ax2, ax3, ax4, ax5, ax6, ax7);
    kB0 = slot_key_T(0, lane, startB, lenB, Ns, Ns, srcT, srcn, niB, bx0, bx1, bx2, bx3, bx4, bx5, bx6, bx7);
    if (NSL > 1) {
        if (lenA > 64)  kA1 = slot_key_T(1, lane, startA, lenA, Ns, Ns, srcT, srcn, niA, ax0, ax1, ax2, ax3, ax4, ax5, ax6, ax7);
        if (lenB > 64)  kB1 = slot_key_T(1, lane, startB, lenB, Ns, Ns, srcT, srcn, niB, bx0, bx1, bx2, bx3, bx4, bx5, bx6, bx7);
    }
    if (NSL > 2) {
        if (lenA > 128) kA2 = slot_key_T(2, lane, startA, lenA, Ns, Ns, srcT, srcn, niA, ax0, ax1, ax2, ax3, ax4, ax5, ax6, ax7);
        if (lenB > 128) kB2 = slot_key_T(2, lane, startB, lenB, Ns, Ns, srcT, srcn, niB, bx0, bx1, bx2, bx3, bx4, bx5, bx6, bx7);
    }
    if (NSL > 3) {
        if (lenA > 192) kA3 = slot_key_T(3, lane, startA, lenA, Ns, Ns, srcT, srcn, niA, ax0, ax1, ax2, ax3, ax4, ax5, ax6, ax7);
        if (lenB > 192) kB3 = slot_key_T(3, lane, startB, lenB, Ns, Ns, srcT, srcn, niB, bx0, bx1, bx2, bx3, bx4, bx5, bx6, bx7);
    }
    if (NSL > 4) {
        if (lenA > 256) kA4 = slot_key_T(4, lane, startA, lenA, Ns, Ns, srcT, srcn, niA, ax0, ax1, ax2, ax3, ax4, ax5, ax6, ax7);
        if (lenB > 256) kB4 = slot_key_T(4, lane, startB, lenB, Ns, Ns, srcT, srcn, niB, bx0, bx1, bx2, bx3, bx4, bx5, bx6, bx7);
    }
    if (NSL > 5) {
        if (lenA > 320) kA5 = slot_key_T(5, lane, startA, lenA, Ns, Ns, srcT, srcn, niA, ax0, ax1, ax2, ax3, ax4, ax5, ax6, ax7);
        if (lenB > 320) kB5 = slot_key_T(5, lane, startB, lenB, Ns, Ns, srcT, srcn, niB, bx0, bx1, bx2, bx3, bx4, bx5, bx6, bx7);
    }

    unsigned loA = 0u, hiA = 0xFFFFFFFFu, loB = 0u, hiB = 0xFFFFFFFFu;
#pragma unroll 1
    for (int it = 0; it < 32; ++it) {
        const unsigned mA = loA + ((hiA - loA) >> 1);
        const unsigned mB = loB + ((hiB - loB) >> 1);
        int cA = __popcll(__ballot(kA0 <= mA));
        int cB = __popcll(__ballot(kB0 <= mB));
        if (NSL > 1) { cA += __popcll(__ballot(kA1 <= mA)); cB += __popcll(__ballot(kB1 <= mB)); }
        if (NSL > 2) { cA += __popcll(__ballot(kA2 <= mA)); cB += __popcll(__ballot(kB2 <= mB)); }
        if (NSL > 3) { cA += __popcll(__ballot(kA3 <= mA)); cB += __popcll(__ballot(kB3 <= mB)); }
        if (NSL > 4) { cA += __popcll(__ballot(kA4 <= mA)); cB += __popcll(__ballot(kB4 <= mB)); }
        if (NSL > 5) { cA += __popcll(__ballot(kA5 <= mA)); cB += __popcll(__ballot(kB5 <= mB)); }
        if (loA != hiA) { if (cA >= 16) hiA = mA; else loA = mA + 1; }
        if (loB != hiB) { if (cB >= 16) hiB = mB; else loB = mB + 1; }
        if (loA == hiA && loB == hiB) break;
    }

    select_compact<NSL>(kA0, kA1, kA2, kA3, kA4, kA5, loA, startA, Ns, widxA, lane);
    select_compact<NSL>(kB0, kB1, kB2, kB3, kB4, kB5, loB, startB, Ns, widxB, lane);

    const int c = lane & 31;
    const int n0 = lane >> 3, qq = lane & 7;
    const int n1 = n0 + 8;
    int jA0 = widxA[n0]; jA0 = ((unsigned)jA0 < (unsigned)Ns) ? jA0 : 0;
    int jA1 = widxA[n1]; jA1 = ((unsigned)jA1 < (unsigned)Ns) ? jA1 : 0;
    int jB0 = widxB[n0]; jB0 = ((unsigned)jB0 < (unsigned)Ns) ? jB0 : 0;
    int jB1 = widxB[n1]; jB1 = ((unsigned)jB1 < (unsigned)Ns) ? jB1 : 0;
    const float4* S = reinterpret_cast<const float4*>(srcf);
    const float4 rA0 = S[(size_t)jA0 * 8 + qq];
    const float4 rA1 = S[(size_t)jA1 * 8 + qq];
    const float4 rB0 = S[(size_t)jB0 * 8 + qq];
    const float4 rB1 = S[(size_t)jB1 * 8 + qq];

    float baseA = Bc[c];
    baseA = wdot4(W, c, 0, ax0, baseA); baseA = wdot4(W, c, 1, ax1, baseA);
    baseA = wdot4(W, c, 2, ax2, baseA); baseA = wdot4(W, c, 3, ax3, baseA);
    baseA = wdot4(W, c, 4, ax4, baseA); baseA = wdot4(W, c, 5, ax5, baseA);
    baseA = wdot4(W, c, 6, ax6, baseA); baseA = wdot4(W, c, 7, ax7, baseA);
    float dA = 0.0f;
    dA = dot4(ax0, w20, dA); dA = dot4(ax1, w21, dA); dA = dot4(ax2, w22, dA); dA = dot4(ax3, w23, dA);
    dA = dot4(ax4, w24, dA); dA = dot4(ax5, w25, dA); dA = dot4(ax6, w26, dA); dA = dot4(ax7, w27, dA);
    const float cbaseA = baseA - dA;

    float baseB = Bc[c];
    baseB = wdot4(W, c, 0, bx0, baseB); baseB = wdot4(W, c, 1, bx1, baseB);
    baseB = wdot4(W, c, 2, bx2, baseB); baseB = wdot4(W, c, 3, bx3, baseB);
    baseB = wdot4(W, c, 4, bx4, baseB); baseB = wdot4(W, c, 5, bx5, baseB);
    baseB = wdot4(W, c, 6, bx6, baseB); baseB = wdot4(W, c, 7, bx7, baseB);
    float dB = 0.0f;
    dB = dot4(bx0, w20, dB); dB = dot4(bx1, w21, dB); dB = dot4(bx2, w22, dB); dB = dot4(bx3, w23, dB);
    dB = dot4(bx4, w24, dB); dB = dot4(bx5, w25, dB); dB = dot4(bx6, w26, dB); dB = dot4(bx7, w27, dB);
    const float cbaseB = baseB - dB;

    sNbrA[n0 * 8 + qq] = rA0;
    sNbrA[n1 * 8 + qq] = rA1;
    sNbrB[n0 * 8 + qq] = rB0;
    sNbrB[n1 * 8 + qq] = rB1;
    __builtin_amdgcn_wave_barrier();

    const int half = lane >> 5;
    float vmA = -__builtin_huge_valf(), vmB = -__builtin_huge_valf();
#pragma unroll 1
    for (int r = 0; r < 8; ++r) {
        const float4* nA = sNbrA + (2 * r + half) * 8;
        const float4* nB = sNbrB + (2 * r + half) * 8;
        float accA = cbaseA, accB = cbaseB;
        accA = dot4(nA[0], w20, accA); accB = dot4(nB[0], w20, accB);
        accA = dot4(nA[1], w21, accA); accB = dot4(nB[1], w21, accB);
        accA = dot4(nA[2], w22, accA); accB = dot4(nB[2], w22, accB);
        accA = dot4(nA[3], w23, accA); accB = dot4(nB[3], w23, accB);
        accA = dot4(nA[4], w24, accA); accB = dot4(nB[4], w24, accB);
        accA = dot4(nA[5], w25, accA); accB = dot4(nB[5], w25, accB);
        accA = dot4(nA[6], w26, accA); accB = dot4(nB[6], w26, accB);
        accA = dot4(nA[7], w27, accA); accB = dot4(nB[7], w27, accB);
        vmA = fmaxf(vmA, LRELU(accA));
        vmB = fmaxf(vmB, LRELU(accB));
    }
    vmA = fmaxf(vmA, __shfl_xor(vmA, 32));
    vmB = fmaxf(vmB, __shfl_xor(vmB, 32));
    vOutA = vmA;
    vOutB = vmB;
}

// ---------------------------------------------------------------------------
// Kernel 1: both MLP2 encoders + sq norms + group-offset tables + transposed
// feature copies.
// ---------------------------------------------------------------------------
__launch_bounds__(256)
__global__ void encode_kernel(const float* __restrict__ x_pfc, const float* __restrict__ x_vtx,
                              const int* __restrict__ bpfc, const int* __restrict__ bvtx,
                              const float* __restrict__ pw1, const float* __restrict__ pb1,
                              const float* __restrict__ pw2, const float* __restrict__ pb2,
                              const float* __restrict__ vw1, const float* __restrict__ vb1,
                              const float* __restrict__ vw2, const float* __restrict__ vb2,
                              float* __restrict__ pfc_enc, float* __restrict__ pfc_norm,
                              float* __restrict__ vtx_enc, float* __restrict__ vtx_norm,
                              float* __restrict__ pfc_encT, float* __restrict__ vtx_encT,
                              int* __restrict__ goff_pfc, int* __restrict__ goff_vtx) {
    __shared__ float h1s[8][32];
    const int t = threadIdx.x;
    const int c = t & 31;
    const int nl = t >> 5;

    if (blockIdx.x == 0) {
        if (t < 33) goff_pfc[t] = lower_bound_i(bpfc, 8192, t);
        else if (t >= 64 && t < 97) goff_vtx[t - 64] = lower_bound_i(bvtx, 2048, t - 64);
    }

    const bool is_pfc = (blockIdx.x < 1024);
    const int node = (is_pfc ? blockIdx.x : (blockIdx.x - 1024)) * 8 + nl;
    const int din = is_pfc ? 7 : 4;
    const int Nn = is_pfc ? 8192 : 2048;
    const float* __restrict__ xin = is_pfc ? (x_pfc + node * 7) : (x_vtx + node * 4);
    const float* __restrict__ w1 = is_pfc ? pw1 : vw1;
    const float* __restrict__ b1 = is_pfc ? pb1 : vb1;
    const float* __restrict__ w2 = is_pfc ? pw2 : vw2;
    const float* __restrict__ b2 = is_pfc ? pb2 : vb2;
    float* __restrict__ enc  = is_pfc ? pfc_enc : vtx_enc;
    float* __restrict__ encT = is_pfc ? pfc_encT : vtx_encT;
    float* __restrict__ nrm  = is_pfc ? pfc_norm : vtx_norm;

    float h1 = b1[c];
    for (int d = 0; d < din; ++d) h1 = fmaf(xin[d], w1[d * 32 + c], h1);
    h1 = LRELU(h1);
    h1s[nl][c] = h1;
    __syncthreads();

    float h2 = b2[c];
#pragma unroll
    for (int d = 0; d < 32; ++d) h2 = fmaf(h1s[nl][d], w2[d * 32 + c], h2);
    h2 = LRELU(h2);
    enc[node * 32 + c] = h2;
    encT[(size_t)c * Nn + node] = h2;

    float s = h2 * h2;
#pragma unroll
    for (int m = 16; m >= 1; m >>= 1) s += __shfl_xor(s, m);
    if (c == 0) nrm[node] = s;
}

// ---------------------------------------------------------------------------
// Kernel 2: fused conv1 + conv2 + OUTPUT MLP. TWO nodes per wave, 128-thr
// blocks. MLP weights staged to LDS once per block (R8's regression was
// per-fma GLOBAL weight reads; this is one coalesced stage + ds broadcasts).
// Only block barrier = the staging sync. Kills the out_mlp dispatch and the
// feats2 global roundtrip (R9+ shows ~105us of non-conv time — dispatch
// serialization is the target).
// ---------------------------------------------------------------------------
__launch_bounds__(128)
__global__ void fused_conv_mlp_kernel(
    const float* __restrict__ pfc_enc, const float* __restrict__ pfc_encT,
    const float* __restrict__ n_pfc,
    const float* __restrict__ vtx_enc, const float* __restrict__ vtx_encT,
    const float* __restrict__ n_vtx,
    const int* __restrict__ bpfc,
    const int* __restrict__ goff_pfc, const int* __restrict__ goff_vtx,
    const float* __restrict__ W, const float* __restrict__ Bc,
    const float* __restrict__ ow1, const float* __restrict__ ob1,
    const float* __restrict__ ow2, const float* __restrict__ ob2,
    const float* __restrict__ ow3, const float* __restrict__ ob3,
    const float* __restrict__ ow4, const float* __restrict__ ob4,
    float* __restrict__ dout, int N)
{
    __shared__ __align__(16) float4 sNbr[2][2][128];   // [wave][node]
    __shared__ int widx[2][2][16];
    __shared__ __align__(16) float sRow[2][2][32];
    __shared__ float sEx1[2][2][64];
    __shared__ __align__(16) float sW1m[32 * 64];      // out_w1
    __shared__ __align__(16) float sW2m[64 * 32];      // out_w2
    __shared__ float sW3m[32 * 4];
    __shared__ float sB1m[64], sB2m[32];

    const int t = threadIdx.x;
    const int lane = t & 63;
    const int w = t >> 6;
    const int b = blockIdx.x;              // 2048 blocks x 4 nodes
    const int xcd = b & 7, chunk = b >> 3;
    const int iA = xcd * 1024 + chunk * 4 + w * 2;
    const int iB = iA + 1;
    const int c = lane & 31;

    // Stage MLP weights (coalesced float4) — the only block barrier.
    {
        const float4* s1 = reinterpret_cast<const float4*>(ow1);
        const float4* s2 = reinterpret_cast<const float4*>(ow2);
        float4* d1 = reinterpret_cast<float4*>(sW1m);
        float4* d2 = reinterpret_cast<float4*>(sW2m);
#pragma unroll
        for (int k = 0; k < 4; ++k) { d1[t + 128 * k] = s1[t + 128 * k]; d2[t + 128 * k] = s2[t + 128 * k]; }
        if (t < 128) sW3m[t] = ow3[t];
        if (t < 64)  sB1m[t] = ob1[t];
        else if (t >= 64 && t < 96) sB2m[t - 64] = ob2[t - 64];
    }
    __syncthreads();

    // W2 column (rows 32..63, col c) into 8 float4 regs (L2-hot broadcast)
    const float4 w20 = make_float4(W[32 * 32 + c], W[33 * 32 + c], W[34 * 32 + c], W[35 * 32 + c]);
    const float4 w21 = make_float4(W[36 * 32 + c], W[37 * 32 + c], W[38 * 32 + c], W[39 * 32 + c]);
    const float4 w22 = make_float4(W[40 * 32 + c], W[41 * 32 + c], W[42 * 32 + c], W[43 * 32 + c]);
    const float4 w23 = make_float4(W[44 * 32 + c], W[45 * 32 + c], W[46 * 32 + c], W[47 * 32 + c]);
    const float4 w24 = make_float4(W[48 * 32 + c], W[49 * 32 + c], W[50 * 32 + c], W[51 * 32 + c]);
    const float4 w25 = make_float4(W[52 * 32 + c], W[53 * 32 + c], W[54 * 32 + c], W[55 * 32 + c]);
    const float4 w26 = make_float4(W[56 * 32 + c], W[57 * 32 + c], W[58 * 32 + c], W[59 * 32 + c]);
    const float4 w27 = make_float4(W[60 * 32 + c], W[61 * 32 + c], W[62 * 32 + c], W[63 * 32 + c]);

    float4* sNbrA = &sNbr[w][0][0];
    float4* sNbrB = &sNbr[w][1][0];
    int* widxA = &widx[w][0][0];
    int* widxB = &widx[w][1][0];

    const int gA = bpfc[iA], gB = bpfc[iB];

    // ---- conv1: src = dst = pfc ----
    const float4* xA = reinterpret_cast<const float4*>(pfc_enc + (size_t)iA * 32);
    const float4 a0 = xA[0], a1 = xA[1], a2 = xA[2], a3 = xA[3],
                 a4 = xA[4], a5 = xA[5], a6 = xA[6], a7 = xA[7];
    const float4* xB = reinterpret_cast<const float4*>(pfc_enc + (size_t)iB * 32);
    const float4 b0 = xB[0], b1 = xB[1], b2 = xB[2], b3 = xB[3],
                 b4 = xB[4], b5 = xB[5], b6 = xB[6], b7 = xB[7];
    const float niA = n_pfc[iA], niB = n_pfc[iB];
    const int s1A = goff_pfc[gA], len1A = min(goff_pfc[gA + 1] - s1A, 384);
    const int s1B = goff_pfc[gB], len1B = min(goff_pfc[gB + 1] - s1B, 384);

    float v1A, v1B;
    {
        const int nsl = (max(len1A, len1B) + 63) >> 6;
        if (nsl <= 4)
            conv_pair<4>(a0, a1, a2, a3, a4, a5, a6, a7, niA, s1A, len1A,
                         b0, b1, b2, b3, b4, b5, b6, b7, niB, s1B, len1B,
                         pfc_enc, pfc_encT, n_pfc, 8192, W, Bc,
                         w20, w21, w22, w23, w24, w25, w26, w27,
                         sNbrA, sNbrB, widxA, widxB, lane, v1A, v1B);
        else
            conv_pair<6>(a0, a1, a2, a3, a4, a5, a6, a7, niA, s1A, len1A,
                         b0, b1, b2, b3, b4, b5, b6, b7, niB, s1B, len1B,
                         pfc_enc, pfc_encT, n_pfc, 8192, W, Bc,
                         w20, w21, w22, w23, w24, w25, w26, w27,
                         sNbrA, sNbrB, widxA, widxB, lane, v1A, v1B);
    }

    if (lane < 32) { sRow[w][0][lane] = v1A; sRow[w][1][lane] = v1B; }
    float nfA = v1A * v1A, nfB = v1B * v1B;
#pragma unroll
    for (int m = 16; m >= 1; m >>= 1) { nfA += __shfl_xor(nfA, m); nfB += __shfl_xor(nfB, m); }
    __builtin_amdgcn_wave_barrier();

    // ---- conv2: dst = feats1 rows (wave-private LDS), src = vtx ----
    const float4* fA = reinterpret_cast<const float4*>(&sRow[w][0][0]);
    const float4 ya0 = fA[0], ya1 = fA[1], ya2 = fA[2], ya3 = fA[3],
                 ya4 = fA[4], ya5 = fA[5], ya6 = fA[6], ya7 = fA[7];
    const float4* fB = reinterpret_cast<const float4*>(&sRow[w][1][0]);
    const float4 yb0 = fB[0], yb1 = fB[1], yb2 = fB[2], yb3 = fB[3],
                 yb4 = fB[4], yb5 = fB[5], yb6 = fB[6], yb7 = fB[7];
    const int s2A = goff_vtx[gA], len2A = min(goff_vtx[gA + 1] - s2A, 128);
    const int s2B = goff_vtx[gB], len2B = min(goff_vtx[gB + 1] - s2B, 128);

    float v2A, v2B;
    conv_pair<2>(ya0, ya1, ya2, ya3, ya4, ya5, ya6, ya7, nfA, s2A, len2A,
                 yb0, yb1, yb2, yb3, yb4, yb5, yb6, yb7, nfB, s2B, len2B,
                 vtx_enc, vtx_encT, n_vtx, 2048, W, Bc,
                 w20, w21, w22, w23, w24, w25, w26, w27,
                 sNbrA, sNbrB, widxA, widxB, lane, v2A, v2B);

    // ---- output MLP 32 -> 64 -> 32 -> 4 -> 1 (lrelu each), wave-private ----
    if (lane < 32) { sRow[w][0][lane] = v2A; sRow[w][1][lane] = v2B; }
    __builtin_amdgcn_wave_barrier();

    // layer 1: 64 outputs per node, one per lane (both nodes interleaved)
    {
        float h1a = sB1m[lane], h1b = sB1m[lane];
#pragma unroll
        for (int d = 0; d < 32; ++d) {
            const float wv = sW1m[d * 64 + lane];
            h1a = fmaf(sRow[w][0][d], wv, h1a);
            h1b = fmaf(sRow[w][1][d], wv, h1b);
        }
        sEx1[w][0][lane] = LRELU(h1a);
        sEx1[w][1][lane] = LRELU(h1b);
    }
    __builtin_amdgcn_wave_barrier();

    // layer 2: 32 outputs per node (both halves duplicate)
    {
        float h2a = sB2m[c], h2b = sB2m[c];
#pragma unroll
        for (int d = 0; d < 64; ++d) {
            const float wv = sW2m[d * 32 + c];
            h2a = fmaf(sEx1[w][0][d], wv, h2a);
            h2b = fmaf(sEx1[w][1][d], wv, h2b);
        }
        if (lane < 32) { sRow[w][0][lane] = LRELU(h2a); sRow[w][1][lane] = LRELU(h2b); }
    }
    __builtin_amdgcn_wave_barrier();

    // layers 3+4 (tiny): every lane computes both nodes fully
    {
        float aa0 = ob3[0], aa1 = ob3[1], aa2 = ob3[2], aa3 = ob3[3];
        float bb0 = ob3[0], bb1 = ob3[1], bb2 = ob3[2], bb3 = ob3[3];
#pragma unroll
        for (int d = 0; d < 32; ++d) {
            const float ea = sRow[w][0][d], eb = sRow[w][1][d];
            const float w0v = sW3m[d * 4 + 0], w1v = sW3m[d * 4 + 1],
                        w2v = sW3m[d * 4 + 2], w3v = sW3m[d * 4 + 3];
            aa0 = fmaf(ea, w0v, aa0); bb0 = fmaf(eb, w0v, bb0);
            aa1 = fmaf(ea, w1v, aa1); bb1 = fmaf(eb, w1v, bb1);
            aa2 = fmaf(ea, w2v, aa2); bb2 = fmaf(eb, w2v, bb2);
            aa3 = fmaf(ea, w3v, aa3); bb3 = fmaf(eb, w3v, bb3);
        }
        aa0 = LRELU(aa0); aa1 = LRELU(aa1); aa2 = LRELU(aa2); aa3 = LRELU(aa3);
        bb0 = LRELU(bb0); bb1 = LRELU(bb1); bb2 = LRELU(bb2); bb3 = LRELU(bb3);
        const float q0 = ow4[0], q1 = ow4[1], q2 = ow4[2], q3 = ow4[3], bz = ob4[0];
        float oA = bz, oB = bz;
        oA = fmaf(aa0, q0, oA); oA = fmaf(aa1, q1, oA); oA = fmaf(aa2, q2, oA); oA = fmaf(aa3, q3, oA);
        oB = fmaf(bb0, q0, oB); oB = fmaf(bb1, q1, oB); oB = fmaf(bb2, q2, oB); oB = fmaf(bb3, q3, oB);
        oA = LRELU(oA); oB = LRELU(oB);

        if (lane == 0) { dout[iA] = oA; dout[iB] = oB; }              // output 0
        if (lane == 1) { dout[N + iA] = (float)gA; dout[N + iB] = (float)gB; }  // output 1
    }
}

// ---------------------------------------------------------------------------
extern "C" void kernel_launch(void* const* d_in, const int* in_sizes, int n_in,
                              void* d_out, int out_size, void* d_ws, size_t ws_size,
                              hipStream_t stream) {
    const float* x_pfc     = (const float*)d_in[0];
    const float* x_vtx     = (const float*)d_in[1];
    const int*   batch_pfc = (const int*)d_in[2];
    const int*   batch_vtx = (const int*)d_in[3];
    const float* pfc_w1 = (const float*)d_in[4];
    const float* pfc_b1 = (const float*)d_in[5];
    const float* pfc_w2 = (const float*)d_in[6];
    const float* pfc_b2 = (const float*)d_in[7];
    const float* vtx_w1 = (const float*)d_in[8];
    const float* vtx_b1 = (const float*)d_in[9];
    const float* vtx_w2 = (const float*)d_in[10];
    const float* vtx_b2 = (const float*)d_in[11];
    const float* conv_w = (const float*)d_in[12];
    const float* conv_b = (const float*)d_in[13];
    const float* out_w1 = (const float*)d_in[14];
    const float* out_b1 = (const float*)d_in[15];
    const float* out_w2 = (const float*)d_in[16];
    const float* out_b2 = (const float*)d_in[17];
    const float* out_w3 = (const float*)d_in[18];
    const float* out_b3 = (const float*)d_in[19];
    const float* out_w4 = (const float*)d_in[20];
    const float* out_b4 = (const float*)d_in[21];

    const int N_PFC = 8192;

    float* ws = (float*)d_ws;
    float* pfc_enc  = ws;                     // 8192*32
    float* vtx_enc  = ws + 262144;            // 2048*32
    float* n_pfc    = ws + 327680;            // 8192
    float* n_vtx    = ws + 335872;            // 2048
    int*   goff_pfc = (int*)(ws + 337920);    // 33 (+pad)
    int*   goff_vtx = (int*)(ws + 337984);    // 33 (+pad)
    float* pfc_encT = ws + 338048;            // 32*8192
    float* vtx_encT = ws + 600192;            // 32*2048  (total 665728 floats)

    encode_kernel<<<1280, 256, 0, stream>>>(x_pfc, x_vtx, batch_pfc, batch_vtx,
                                            pfc_w1, pfc_b1, pfc_w2, pfc_b2,
                                            vtx_w1, vtx_b1, vtx_w2, vtx_b2,
                                            pfc_enc, n_pfc, vtx_enc, n_vtx,
                                            pfc_encT, vtx_encT,
                                            goff_pfc, goff_vtx);

    fused_conv_mlp_kernel<<<2048, 128, 0, stream>>>(
        pfc_enc, pfc_encT, n_pfc, vtx_enc, vtx_encT, n_vtx,
        batch_pfc, goff_pfc, goff_vtx, conv_w, conv_b,
        out_w1, out_b1, out_w2, out_b2, out_w3, out_b3, out_w4, out_b4,
        (float*)d_out, N_PFC);
}

// Round 17
// 172.398 us; speedup vs baseline: 1.3787x; 1.0401x over previous
//
#include <hip/hip_runtime.h>
#include <hip/hip_bf16.h>

#define LRELU(val) ((val) >= 0.0f ? (val) : 0.01f * (val))

__device__ __forceinline__ float dot4(float4 a, float4 b, float acc) {
    return fmaf(a.x, b.x, fmaf(a.y, b.y, fmaf(a.z, b.z, fmaf(a.w, b.w, acc))));
}

__device__ __forceinline__ float wdot4(const float* __restrict__ wbase, int c, int q,
                                       float4 a, float acc) {
    acc = fmaf(a.x, wbase[(4 * q + 0) * 32 + c], acc);
    acc = fmaf(a.y, wbase[(4 * q + 1) * 32 + c], acc);
    acc = fmaf(a.z, wbase[(4 * q + 2) * 32 + c], acc);
    acc = fmaf(a.w, wbase[(4 * q + 3) * 32 + c], acc);
    return acc;
}

__device__ inline int lower_bound_i(const int* __restrict__ a, int n, int v) {
    int lo = 0, hi = n;
    while (lo < hi) {
        int m = (lo + hi) >> 1;
        if (a[m] < v) lo = m + 1; else hi = m;
    }
    return lo;
}

// Sortable 32-bit distance key from the TRANSPOSED feature array (coalesced:
// lane L reads srcT[d*N + start+L+64s]). fmaf tree replicates the row-major
// dot4 chain EXACTLY so keys are bit-identical -> identical selection.
__device__ __forceinline__ unsigned slot_key_T(
    int s, int lane, int start, int len, int Ns, int N,
    const float* __restrict__ srcT, const float* __restrict__ srcn, float ni,
    float4 x0, float4 x1, float4 x2, float4 x3,
    float4 x4, float4 x5, float4 x6, float4 x7)
{
    const int o = lane + 64 * s;
    const bool valid = o < len;
    const int j = valid ? (start + o) : min(start, Ns - 1);
    const float* __restrict__ T = srcT;
    float acc = 0.0f;
    acc = fmaf(T[3 * N + j],  x0.w, acc); acc = fmaf(T[2 * N + j],  x0.z, acc);
    acc = fmaf(T[1 * N + j],  x0.y, acc); acc = fmaf(T[0 * N + j],  x0.x, acc);
    acc = fmaf(T[7 * N + j],  x1.w, acc); acc = fmaf(T[6 * N + j],  x1.z, acc);
    acc = fmaf(T[5 * N + j],  x1.y, acc); acc = fmaf(T[4 * N + j],  x1.x, acc);
    acc = fmaf(T[11 * N + j], x2.w, acc); acc = fmaf(T[10 * N + j], x2.z, acc);
    acc = fmaf(T[9 * N + j],  x2.y, acc); acc = fmaf(T[8 * N + j],  x2.x, acc);
    acc = fmaf(T[15 * N + j], x3.w, acc); acc = fmaf(T[14 * N + j], x3.z, acc);
    acc = fmaf(T[13 * N + j], x3.y, acc); acc = fmaf(T[12 * N + j], x3.x, acc);
    acc = fmaf(T[19 * N + j], x4.w, acc); acc = fmaf(T[18 * N + j], x4.z, acc);
    acc = fmaf(T[17 * N + j], x4.y, acc); acc = fmaf(T[16 * N + j], x4.x, acc);
    acc = fmaf(T[23 * N + j], x5.w, acc); acc = fmaf(T[22 * N + j], x5.z, acc);
    acc = fmaf(T[21 * N + j], x5.y, acc); acc = fmaf(T[20 * N + j], x5.x, acc);
    acc = fmaf(T[27 * N + j], x6.w, acc); acc = fmaf(T[26 * N + j], x6.z, acc);
    acc = fmaf(T[25 * N + j], x6.y, acc); acc = fmaf(T[24 * N + j], x6.x, acc);
    acc = fmaf(T[31 * N + j], x7.w, acc); acc = fmaf(T[30 * N + j], x7.z, acc);
    acc = fmaf(T[29 * N + j], x7.y, acc); acc = fmaf(T[28 * N + j], x7.x, acc);
    const float d2 = (ni + srcn[j]) - 2.0f * acc;   // reference distance formula
    unsigned u = __float_as_uint(d2);
    u = (d2 < 0.0f) ? ~u : (u | 0x80000000u);       // monotone float->uint map
    return valid ? u : 0xFFFFFFFFu;
}

// Membership + compaction for one node (exact lax.top_k tie semantics).
template <int NSL>
__device__ __forceinline__ void select_compact(
    unsigned k0, unsigned k1, unsigned k2, unsigned k3, unsigned k4, unsigned k5,
    unsigned T, int start, int Ns, int* __restrict__ widxW, int lane)
{
    const unsigned long long below = (1ull << lane) - 1ull;
    int m = __popcll(__ballot(k0 < T));
    if (NSL > 1) m += __popcll(__ballot(k1 < T));
    if (NSL > 2) m += __popcll(__ballot(k2 < T));
    if (NSL > 3) m += __popcll(__ballot(k3 < T));
    if (NSL > 4) m += __popcll(__ballot(k4 < T));
    if (NSL > 5) m += __popcll(__ballot(k5 < T));
    const int need = 16 - m;
    const unsigned long long e0 = __ballot(k0 == T);
    const unsigned long long e1 = (NSL > 1) ? __ballot(k1 == T) : 0ull;
    const unsigned long long e2 = (NSL > 2) ? __ballot(k2 == T) : 0ull;
    const unsigned long long e3 = (NSL > 3) ? __ballot(k3 == T) : 0ull;
    const unsigned long long e4 = (NSL > 4) ? __ballot(k4 == T) : 0ull;
    const int eq0 = __popcll(e0), eq1 = eq0 + __popcll(e1), eq2 = eq1 + __popcll(e2),
              eq3 = eq2 + __popcll(e3), eq4 = eq3 + __popcll(e4);
    const bool sel0 = (k0 < T) || ((k0 == T) && (__popcll(e0 & below) < need));
    const bool sel1 = (NSL > 1) && ((k1 < T) || ((k1 == T) && (eq0 + __popcll(e1 & below) < need)));
    const bool sel2 = (NSL > 2) && ((k2 < T) || ((k2 == T) && (eq1 + __popcll(e2 & below) < need)));
    const bool sel3 = (NSL > 3) && ((k3 < T) || ((k3 == T) && (eq2 + __popcll(e3 & below) < need)));
    const bool sel4 = (NSL > 4) && ((k4 < T) || ((k4 == T) && (eq3 + __popcll(e4 & below) < need)));
    const bool sel5 = (NSL > 5) && ((k5 < T) || ((k5 == T) && (eq4 + __popcll(__ballot(k5 == T) & below) < need)));
    const unsigned long long s0 = __ballot(sel0);
    const unsigned long long s1 = __ballot(sel1);
    const unsigned long long s2 = __ballot(sel2);
    const unsigned long long s3 = __ballot(sel3);
    const unsigned long long s4 = __ballot(sel4);
    const unsigned long long s5 = __ballot(sel5);
    const int c0 = __popcll(s0), c1 = c0 + __popcll(s1), c2 = c1 + __popcll(s2),
              c3 = c2 + __popcll(s3), c4 = c3 + __popcll(s4);
    if (lane < 16) widxW[lane] = min(start, Ns - 1);   // fallback, len<16 never in practice
    __builtin_amdgcn_wave_barrier();
    if (sel0) widxW[__popcll(s0 & below)] = start + lane;
    if (NSL > 1 && sel1) widxW[c0 + __popcll(s1 & below)] = start + lane + 64;
    if (NSL > 2 && sel2) widxW[c1 + __popcll(s2 & below)] = start + lane + 128;
    if (NSL > 3 && sel3) widxW[c2 + __popcll(s3 & below)] = start + lane + 192;
    if (NSL > 4 && sel4) widxW[c3 + __popcll(s4 & below)] = start + lane + 256;
    if (NSL > 5 && sel5) widxW[c4 + __popcll(s5 & below)] = start + lane + 320;
    __builtin_amdgcn_wave_barrier();
}

// ---------------------------------------------------------------------------
// TWO independent nodes per wave, all phases interleaved. Distances from the
// transposed array (coalesced); neighbor rows from the row-major array.
// Ballot bisection (lo seeded at 0x80000000 — all valid keys have bit31 set)
// + exact tie-order compaction. No block barriers.
// ---------------------------------------------------------------------------
template <int NSL>
__device__ __forceinline__ void conv_pair(
    float4 ax0, float4 ax1, float4 ax2, float4 ax3,
    float4 ax4, float4 ax5, float4 ax6, float4 ax7,
    float niA, int startA, int lenA,
    float4 bx0, float4 bx1, float4 bx2, float4 bx3,
    float4 bx4, float4 bx5, float4 bx6, float4 bx7,
    float niB, int startB, int lenB,
    const float* __restrict__ srcf, const float* __restrict__ srcT,
    const float* __restrict__ srcn, int Ns,
    const float* __restrict__ W, const float* __restrict__ Bc,
    float4 w20, float4 w21, float4 w22, float4 w23,
    float4 w24, float4 w25, float4 w26, float4 w27,
    float4* __restrict__ sNbrA, float4* __restrict__ sNbrB,
    int* __restrict__ widxA, int* __restrict__ widxB,
    int lane, float& vOutA, float& vOutB)
{
    unsigned kA0 = 0xFFFFFFFFu, kA1 = 0xFFFFFFFFu, kA2 = 0xFFFFFFFFu,
             kA3 = 0xFFFFFFFFu, kA4 = 0xFFFFFFFFu, kA5 = 0xFFFFFFFFu;
    unsigned kB0 = 0xFFFFFFFFu, kB1 = 0xFFFFFFFFu, kB2 = 0xFFFFFFFFu,
             kB3 = 0xFFFFFFFFu, kB4 = 0xFFFFFFFFu, kB5 = 0xFFFFFFFFu;
    kA0 = slot_key_T(0, lane, startA, lenA, Ns, Ns, srcT, srcn, niA, ax0, ax1, ax2, ax3, ax4, ax5, ax6, ax7);
    kB0 = slot_key_T(0, lane, startB, lenB, Ns, Ns, srcT, srcn, niB, bx0, bx1, bx2, bx3, bx4, bx5, bx6, bx7);
    if (NSL > 1) {
        if (lenA > 64)  kA1 = slot_key_T(1, lane, startA, lenA, Ns, Ns, srcT, srcn, niA, ax0, ax1, ax2, ax3, ax4, ax5, ax6, ax7);
        if (lenB > 64)  kB1 = slot_key_T(1, lane, startB, lenB, Ns, Ns, srcT, srcn, niB, bx0, bx1, bx2, bx3, bx4, bx5, bx6, bx7);
    }
    if (NSL > 2) {
        if (lenA > 128) kA2 = slot_key_T(2, lane, startA, lenA, Ns, Ns, srcT, srcn, niA, ax0, ax1, ax2, ax3, ax4, ax5, ax6, ax7);
        if (lenB > 128) kB2 = slot_key_T(2, lane, startB, lenB, Ns, Ns, srcT, srcn, niB, bx0, bx1, bx2, bx3, bx4, bx5, bx6, bx7);
    }
    if (NSL > 3) {
        if (lenA > 192) kA3 = slot_key_T(3, lane, startA, lenA, Ns, Ns, srcT, srcn, niA, ax0, ax1, ax2, ax3, ax4, ax5, ax6, ax7);
        if (lenB > 192) kB3 = slot_key_T(3, lane, startB, lenB, Ns, Ns, srcT, srcn, niB, bx0, bx1, bx2, bx3, bx4, bx5, bx6, bx7);
    }
    if (NSL > 4) {
        if (lenA > 256) kA4 = slot_key_T(4, lane, startA, lenA, Ns, Ns, srcT, srcn, niA, ax0, ax1, ax2, ax3, ax4, ax5, ax6, ax7);
        if (lenB > 256) kB4 = slot_key_T(4, lane, startB, lenB, Ns, Ns, srcT, srcn, niB, bx0, bx1, bx2, bx3, bx4, bx5, bx6, bx7);
    }
    if (NSL > 5) {
        if (lenA > 320) kA5 = slot_key_T(5, lane, startA, lenA, Ns, Ns, srcT, srcn, niA, ax0, ax1, ax2, ax3, ax4, ax5, ax6, ax7);
        if (lenB > 320) kB5 = slot_key_T(5, lane, startB, lenB, Ns, Ns, srcT, srcn, niB, bx0, bx1, bx2, bx3, bx4, bx5, bx6, bx7);
    }

    unsigned loA = 0x80000000u, hiA = 0xFFFFFFFFu, loB = 0x80000000u, hiB = 0xFFFFFFFFu;
#pragma unroll 1
    for (int it = 0; it < 31; ++it) {
        const unsigned mA = loA + ((hiA - loA) >> 1);
        const unsigned mB = loB + ((hiB - loB) >> 1);
        int cA = __popcll(__ballot(kA0 <= mA));
        int cB = __popcll(__ballot(kB0 <= mB));
        if (NSL > 1) { cA += __popcll(__ballot(kA1 <= mA)); cB += __popcll(__ballot(kB1 <= mB)); }
        if (NSL > 2) { cA += __popcll(__ballot(kA2 <= mA)); cB += __popcll(__ballot(kB2 <= mB)); }
        if (NSL > 3) { cA += __popcll(__ballot(kA3 <= mA)); cB += __popcll(__ballot(kB3 <= mB)); }
        if (NSL > 4) { cA += __popcll(__ballot(kA4 <= mA)); cB += __popcll(__ballot(kB4 <= mB)); }
        if (NSL > 5) { cA += __popcll(__ballot(kA5 <= mA)); cB += __popcll(__ballot(kB5 <= mB)); }
        if (loA != hiA) { if (cA >= 16) hiA = mA; else loA = mA + 1; }
        if (loB != hiB) { if (cB >= 16) hiB = mB; else loB = mB + 1; }
        if (loA == hiA && loB == hiB) break;
    }

    select_compact<NSL>(kA0, kA1, kA2, kA3, kA4, kA5, loA, startA, Ns, widxA, lane);
    select_compact<NSL>(kB0, kB1, kB2, kB3, kB4, kB5, loB, startB, Ns, widxB, lane);

    const int c = lane & 31;
    const int n0 = lane >> 3, qq = lane & 7;
    const int n1 = n0 + 8;
    int jA0 = widxA[n0]; jA0 = ((unsigned)jA0 < (unsigned)Ns) ? jA0 : 0;
    int jA1 = widxA[n1]; jA1 = ((unsigned)jA1 < (unsigned)Ns) ? jA1 : 0;
    int jB0 = widxB[n0]; jB0 = ((unsigned)jB0 < (unsigned)Ns) ? jB0 : 0;
    int jB1 = widxB[n1]; jB1 = ((unsigned)jB1 < (unsigned)Ns) ? jB1 : 0;
    const float4* S = reinterpret_cast<const float4*>(srcf);
    const float4 rA0 = S[(size_t)jA0 * 8 + qq];
    const float4 rA1 = S[(size_t)jA1 * 8 + qq];
    const float4 rB0 = S[(size_t)jB0 * 8 + qq];
    const float4 rB1 = S[(size_t)jB1 * 8 + qq];

    float baseA = Bc[c];
    baseA = wdot4(W, c, 0, ax0, baseA); baseA = wdot4(W, c, 1, ax1, baseA);
    baseA = wdot4(W, c, 2, ax2, baseA); baseA = wdot4(W, c, 3, ax3, baseA);
    baseA = wdot4(W, c, 4, ax4, baseA); baseA = wdot4(W, c, 5, ax5, baseA);
    baseA = wdot4(W, c, 6, ax6, baseA); baseA = wdot4(W, c, 7, ax7, baseA);
    float dA = 0.0f;
    dA = dot4(ax0, w20, dA); dA = dot4(ax1, w21, dA); dA = dot4(ax2, w22, dA); dA = dot4(ax3, w23, dA);
    dA = dot4(ax4, w24, dA); dA = dot4(ax5, w25, dA); dA = dot4(ax6, w26, dA); dA = dot4(ax7, w27, dA);
    const float cbaseA = baseA - dA;

    float baseB = Bc[c];
    baseB = wdot4(W, c, 0, bx0, baseB); baseB = wdot4(W, c, 1, bx1, baseB);
    baseB = wdot4(W, c, 2, bx2, baseB); baseB = wdot4(W, c, 3, bx3, baseB);
    baseB = wdot4(W, c, 4, bx4, baseB); baseB = wdot4(W, c, 5, bx5, baseB);
    baseB = wdot4(W, c, 6, bx6, baseB); baseB = wdot4(W, c, 7, bx7, baseB);
    float dB = 0.0f;
    dB = dot4(bx0, w20, dB); dB = dot4(bx1, w21, dB); dB = dot4(bx2, w22, dB); dB = dot4(bx3, w23, dB);
    dB = dot4(bx4, w24, dB); dB = dot4(bx5, w25, dB); dB = dot4(bx6, w26, dB); dB = dot4(bx7, w27, dB);
    const float cbaseB = baseB - dB;

    sNbrA[n0 * 8 + qq] = rA0;
    sNbrA[n1 * 8 + qq] = rA1;
    sNbrB[n0 * 8 + qq] = rB0;
    sNbrB[n1 * 8 + qq] = rB1;
    __builtin_amdgcn_wave_barrier();

    const int half = lane >> 5;
    float vmA = -__builtin_huge_valf(), vmB = -__builtin_huge_valf();
#pragma unroll 1
    for (int r = 0; r < 8; ++r) {
        const float4* nA = sNbrA + (2 * r + half) * 8;
        const float4* nB = sNbrB + (2 * r + half) * 8;
        float accA = cbaseA, accB = cbaseB;
        accA = dot4(nA[0], w20, accA); accB = dot4(nB[0], w20, accB);
        accA = dot4(nA[1], w21, accA); accB = dot4(nB[1], w21, accB);
        accA = dot4(nA[2], w22, accA); accB = dot4(nB[2], w22, accB);
        accA = dot4(nA[3], w23, accA); accB = dot4(nB[3], w23, accB);
        accA = dot4(nA[4], w24, accA); accB = dot4(nB[4], w24, accB);
        accA = dot4(nA[5], w25, accA); accB = dot4(nB[5], w25, accB);
        accA = dot4(nA[6], w26, accA); accB = dot4(nB[6], w26, accB);
        accA = dot4(nA[7], w27, accA); accB = dot4(nB[7], w27, accB);
        vmA = fmaxf(vmA, LRELU(accA));
        vmB = fmaxf(vmB, LRELU(accB));
    }
    vmA = fmaxf(vmA, __shfl_xor(vmA, 32));
    vmB = fmaxf(vmB, __shfl_xor(vmB, 32));
    vOutA = vmA;
    vOutB = vmB;
}

// ---------------------------------------------------------------------------
// Kernel 1: both MLP2 encoders + sq norms + group-offset tables + transposed
// feature copies.
// ---------------------------------------------------------------------------
__launch_bounds__(256)
__global__ void encode_kernel(const float* __restrict__ x_pfc, const float* __restrict__ x_vtx,
                              const int* __restrict__ bpfc, const int* __restrict__ bvtx,
                              const float* __restrict__ pw1, const float* __restrict__ pb1,
                              const float* __restrict__ pw2, const float* __restrict__ pb2,
                              const float* __restrict__ vw1, const float* __restrict__ vb1,
                              const float* __restrict__ vw2, const float* __restrict__ vb2,
                              float* __restrict__ pfc_enc, float* __restrict__ pfc_norm,
                              float* __restrict__ vtx_enc, float* __restrict__ vtx_norm,
                              float* __restrict__ pfc_encT, float* __restrict__ vtx_encT,
                              int* __restrict__ goff_pfc, int* __restrict__ goff_vtx) {
    __shared__ float h1s[8][32];
    const int t = threadIdx.x;
    const int c = t & 31;
    const int nl = t >> 5;

    if (blockIdx.x == 0) {
        if (t < 33) goff_pfc[t] = lower_bound_i(bpfc, 8192, t);
        else if (t >= 64 && t < 97) goff_vtx[t - 64] = lower_bound_i(bvtx, 2048, t - 64);
    }

    const bool is_pfc = (blockIdx.x < 1024);
    const int node = (is_pfc ? blockIdx.x : (blockIdx.x - 1024)) * 8 + nl;
    const int din = is_pfc ? 7 : 4;
    const int Nn = is_pfc ? 8192 : 2048;
    const float* __restrict__ xin = is_pfc ? (x_pfc + node * 7) : (x_vtx + node * 4);
    const float* __restrict__ w1 = is_pfc ? pw1 : vw1;
    const float* __restrict__ b1 = is_pfc ? pb1 : vb1;
    const float* __restrict__ w2 = is_pfc ? pw2 : vw2;
    const float* __restrict__ b2 = is_pfc ? pb2 : vb2;
    float* __restrict__ enc  = is_pfc ? pfc_enc : vtx_enc;
    float* __restrict__ encT = is_pfc ? pfc_encT : vtx_encT;
    float* __restrict__ nrm  = is_pfc ? pfc_norm : vtx_norm;

    float h1 = b1[c];
    for (int d = 0; d < din; ++d) h1 = fmaf(xin[d], w1[d * 32 + c], h1);
    h1 = LRELU(h1);
    h1s[nl][c] = h1;
    __syncthreads();

    float h2 = b2[c];
#pragma unroll
    for (int d = 0; d < 32; ++d) h2 = fmaf(h1s[nl][d], w2[d * 32 + c], h2);
    h2 = LRELU(h2);
    enc[node * 32 + c] = h2;
    encT[(size_t)c * Nn + node] = h2;

    float s = h2 * h2;
#pragma unroll
    for (int m = 16; m >= 1; m >>= 1) s += __shfl_xor(s, m);
    if (c == 0) nrm[node] = s;
}

// ---------------------------------------------------------------------------
// Kernel 2: fused conv1 + conv2 + output MLP. TWO nodes per wave, 128-thr
// blocks, ZERO block barriers. MLP weights read straight from GLOBAL in the
// tail (L2-hot; layer1/2 are per-lane-column reads = 1-2 lines/instr, all
// independent; layer3/4 are wave-uniform -> s_load). R15's LDS weight stage
// (27.6KB) capped residency at 5 blocks/CU; this keeps LDS ~10KB -> 16
// waves/CU like R14.
// ---------------------------------------------------------------------------
__launch_bounds__(128)
__global__ void fused_conv_mlp_kernel(
    const float* __restrict__ pfc_enc, const float* __restrict__ pfc_encT,
    const float* __restrict__ n_pfc,
    const float* __restrict__ vtx_enc, const float* __restrict__ vtx_encT,
    const float* __restrict__ n_vtx,
    const int* __restrict__ bpfc,
    const int* __restrict__ goff_pfc, const int* __restrict__ goff_vtx,
    const float* __restrict__ W, const float* __restrict__ Bc,
    const float* __restrict__ ow1, const float* __restrict__ ob1,
    const float* __restrict__ ow2, const float* __restrict__ ob2,
    const float* __restrict__ ow3, const float* __restrict__ ob3,
    const float* __restrict__ ow4, const float* __restrict__ ob4,
    float* __restrict__ dout, int N)
{
    __shared__ __align__(16) float4 sNbr[2][2][128];   // [wave][node]
    __shared__ int widx[2][2][16];
    __shared__ __align__(16) float sRow[2][2][32];
    __shared__ float sEx1[2][2][64];

    const int t = threadIdx.x;
    const int lane = t & 63;
    const int w = t >> 6;
    const int b = blockIdx.x;              // 2048 blocks x 4 nodes
    const int xcd = b & 7, chunk = b >> 3;
    const int iA = xcd * 1024 + chunk * 4 + w * 2;
    const int iB = iA + 1;
    const int c = lane & 31;

    // W2 column (rows 32..63, col c) into 8 float4 regs (L2-hot broadcast)
    const float4 w20 = make_float4(W[32 * 32 + c], W[33 * 32 + c], W[34 * 32 + c], W[35 * 32 + c]);
    const float4 w21 = make_float4(W[36 * 32 + c], W[37 * 32 + c], W[38 * 32 + c], W[39 * 32 + c]);
    const float4 w22 = make_float4(W[40 * 32 + c], W[41 * 32 + c], W[42 * 32 + c], W[43 * 32 + c]);
    const float4 w23 = make_float4(W[44 * 32 + c], W[45 * 32 + c], W[46 * 32 + c], W[47 * 32 + c]);
    const float4 w24 = make_float4(W[48 * 32 + c], W[49 * 32 + c], W[50 * 32 + c], W[51 * 32 + c]);
    const float4 w25 = make_float4(W[52 * 32 + c], W[53 * 32 + c], W[54 * 32 + c], W[55 * 32 + c]);
    const float4 w26 = make_float4(W[56 * 32 + c], W[57 * 32 + c], W[58 * 32 + c], W[59 * 32 + c]);
    const float4 w27 = make_float4(W[60 * 32 + c], W[61 * 32 + c], W[62 * 32 + c], W[63 * 32 + c]);

    float4* sNbrA = &sNbr[w][0][0];
    float4* sNbrB = &sNbr[w][1][0];
    int* widxA = &widx[w][0][0];
    int* widxB = &widx[w][1][0];

    const int gA = bpfc[iA], gB = bpfc[iB];

    // ---- conv1: src = dst = pfc ----
    const float4* xA = reinterpret_cast<const float4*>(pfc_enc + (size_t)iA * 32);
    const float4 a0 = xA[0], a1 = xA[1], a2 = xA[2], a3 = xA[3],
                 a4 = xA[4], a5 = xA[5], a6 = xA[6], a7 = xA[7];
    const float4* xB = reinterpret_cast<const float4*>(pfc_enc + (size_t)iB * 32);
    const float4 b0 = xB[0], b1 = xB[1], b2 = xB[2], b3 = xB[3],
                 b4 = xB[4], b5 = xB[5], b6 = xB[6], b7 = xB[7];
    const float niA = n_pfc[iA], niB = n_pfc[iB];
    const int s1A = goff_pfc[gA], len1A = min(goff_pfc[gA + 1] - s1A, 384);
    const int s1B = goff_pfc[gB], len1B = min(goff_pfc[gB + 1] - s1B, 384);

    float v1A, v1B;
    {
        const int nsl = (max(len1A, len1B) + 63) >> 6;
        if (nsl <= 4)
            conv_pair<4>(a0, a1, a2, a3, a4, a5, a6, a7, niA, s1A, len1A,
                         b0, b1, b2, b3, b4, b5, b6, b7, niB, s1B, len1B,
                         pfc_enc, pfc_encT, n_pfc, 8192, W, Bc,
                         w20, w21, w22, w23, w24, w25, w26, w27,
                         sNbrA, sNbrB, widxA, widxB, lane, v1A, v1B);
        else
            conv_pair<6>(a0, a1, a2, a3, a4, a5, a6, a7, niA, s1A, len1A,
                         b0, b1, b2, b3, b4, b5, b6, b7, niB, s1B, len1B,
                         pfc_enc, pfc_encT, n_pfc, 8192, W, Bc,
                         w20, w21, w22, w23, w24, w25, w26, w27,
                         sNbrA, sNbrB, widxA, widxB, lane, v1A, v1B);
    }

    if (lane < 32) { sRow[w][0][lane] = v1A; sRow[w][1][lane] = v1B; }
    float nfA = v1A * v1A, nfB = v1B * v1B;
#pragma unroll
    for (int m = 16; m >= 1; m >>= 1) { nfA += __shfl_xor(nfA, m); nfB += __shfl_xor(nfB, m); }
    __builtin_amdgcn_wave_barrier();

    // ---- conv2: dst = feats1 rows (wave-private LDS), src = vtx ----
    const float4* fA = reinterpret_cast<const float4*>(&sRow[w][0][0]);
    const float4 ya0 = fA[0], ya1 = fA[1], ya2 = fA[2], ya3 = fA[3],
                 ya4 = fA[4], ya5 = fA[5], ya6 = fA[6], ya7 = fA[7];
    const float4* fB = reinterpret_cast<const float4*>(&sRow[w][1][0]);
    const float4 yb0 = fB[0], yb1 = fB[1], yb2 = fB[2], yb3 = fB[3],
                 yb4 = fB[4], yb5 = fB[5], yb6 = fB[6], yb7 = fB[7];
    const int s2A = goff_vtx[gA], len2A = min(goff_vtx[gA + 1] - s2A, 128);
    const int s2B = goff_vtx[gB], len2B = min(goff_vtx[gB + 1] - s2B, 128);

    float v2A, v2B;
    conv_pair<2>(ya0, ya1, ya2, ya3, ya4, ya5, ya6, ya7, nfA, s2A, len2A,
                 yb0, yb1, yb2, yb3, yb4, yb5, yb6, yb7, nfB, s2B, len2B,
                 vtx_enc, vtx_encT, n_vtx, 2048, W, Bc,
                 w20, w21, w22, w23, w24, w25, w26, w27,
                 sNbrA, sNbrB, widxA, widxB, lane, v2A, v2B);

    // ---- output MLP 32 -> 64 -> 32 -> 4 -> 1 (lrelu each), wave-private ----
    if (lane < 32) { sRow[w][0][lane] = v2A; sRow[w][1][lane] = v2B; }
    __builtin_amdgcn_wave_barrier();

    // layer 1: 64 outputs per node, one per lane. Weights from global
    // (column reads: 1-2 lines/instr, independent -> one wait).
    {
        float h1a = ob1[lane], h1b = h1a;
#pragma unroll
        for (int d = 0; d < 32; ++d) {
            const float wv = ow1[d * 64 + lane];
            h1a = fmaf(sRow[w][0][d], wv, h1a);
            h1b = fmaf(sRow[w][1][d], wv, h1b);
        }
        sEx1[w][0][lane] = LRELU(h1a);
        sEx1[w][1][lane] = LRELU(h1b);
    }
    __builtin_amdgcn_wave_barrier();

    // layer 2: 32 outputs per node (both halves duplicate)
    {
        float h2a = ob2[c], h2b = h2a;
#pragma unroll
        for (int d = 0; d < 64; ++d) {
            const float wv = ow2[d * 32 + c];
            h2a = fmaf(sEx1[w][0][d], wv, h2a);
            h2b = fmaf(sEx1[w][1][d], wv, h2b);
        }
        if (lane < 32) { sRow[w][0][lane] = LRELU(h2a); sRow[w][1][lane] = LRELU(h2b); }
    }
    __builtin_amdgcn_wave_barrier();

    // layers 3+4 (tiny): wave-uniform weight reads -> scalar loads
    {
        float aa0 = ob3[0], aa1 = ob3[1], aa2 = ob3[2], aa3 = ob3[3];
        float bb0 = aa0, bb1 = aa1, bb2 = aa2, bb3 = aa3;
#pragma unroll
        for (int d = 0; d < 32; ++d) {
            const float ea = sRow[w][0][d], eb = sRow[w][1][d];
            const float w0v = ow3[d * 4 + 0], w1v = ow3[d * 4 + 1],
                        w2v = ow3[d * 4 + 2], w3v = ow3[d * 4 + 3];
            aa0 = fmaf(ea, w0v, aa0); bb0 = fmaf(eb, w0v, bb0);
            aa1 = fmaf(ea, w1v, aa1); bb1 = fmaf(eb, w1v, bb1);
            aa2 = fmaf(ea, w2v, aa2); bb2 = fmaf(eb, w2v, bb2);
            aa3 = fmaf(ea, w3v, aa3); bb3 = fmaf(eb, w3v, bb3);
        }
        aa0 = LRELU(aa0); aa1 = LRELU(aa1); aa2 = LRELU(aa2); aa3 = LRELU(aa3);
        bb0 = LRELU(bb0); bb1 = LRELU(bb1); bb2 = LRELU(bb2); bb3 = LRELU(bb3);
        const float q0 = ow4[0], q1 = ow4[1], q2 = ow4[2], q3 = ow4[3], bz = ob4[0];
        float oA = bz, oB = bz;
        oA = fmaf(aa0, q0, oA); oA = fmaf(aa1, q1, oA); oA = fmaf(aa2, q2, oA); oA = fmaf(aa3, q3, oA);
        oB = fmaf(bb0, q0, oB); oB = fmaf(bb1, q1, oB); oB = fmaf(bb2, q2, oB); oB = fmaf(bb3, q3, oB);
        oA = LRELU(oA); oB = LRELU(oB);

        if (lane == 0) { dout[iA] = oA; dout[iB] = oB; }              // output 0
        if (lane == 1) { dout[N + iA] = (float)gA; dout[N + iB] = (float)gB; }  // output 1
    }
}

// ---------------------------------------------------------------------------
extern "C" void kernel_launch(void* const* d_in, const int* in_sizes, int n_in,
                              void* d_out, int out_size, void* d_ws, size_t ws_size,
                              hipStream_t stream) {
    const float* x_pfc     = (const float*)d_in[0];
    const float* x_vtx     = (const float*)d_in[1];
    const int*   batch_pfc = (const int*)d_in[2];
    const int*   batch_vtx = (const int*)d_in[3];
    const float* pfc_w1 = (const float*)d_in[4];
    const float* pfc_b1 = (const float*)d_in[5];
    const float* pfc_w2 = (const float*)d_in[6];
    const float* pfc_b2 = (const float*)d_in[7];
    const float* vtx_w1 = (const float*)d_in[8];
    const float* vtx_b1 = (const float*)d_in[9];
    const float* vtx_w2 = (const float*)d_in[10];
    const float* vtx_b2 = (const float*)d_in[11];
    const float* conv_w = (const float*)d_in[12];
    const float* conv_b = (const float*)d_in[13];
    const float* out_w1 = (const float*)d_in[14];
    const float* out_b1 = (const float*)d_in[15];
    const float* out_w2 = (const float*)d_in[16];
    const float* out_b2 = (const float*)d_in[17];
    const float* out_w3 = (const float*)d_in[18];
    const float* out_b3 = (const float*)d_in[19];
    const float* out_w4 = (const float*)d_in[20];
    const float* out_b4 = (const float*)d_in[21];

    const int N_PFC = 8192;

    float* ws = (float*)d_ws;
    float* pfc_enc  = ws;                     // 8192*32
    float* vtx_enc  = ws + 262144;            // 2048*32
    float* n_pfc    = ws + 327680;            // 8192
    float* n_vtx    = ws + 335872;            // 2048
    int*   goff_pfc = (int*)(ws + 337920);    // 33 (+pad)
    int*   goff_vtx = (int*)(ws + 337984);    // 33 (+pad)
    float* pfc_encT = ws + 338048;            // 32*8192
    float* vtx_encT = ws + 600192;            // 32*2048  (total 665728 floats)

    encode_kernel<<<1280, 256, 0, stream>>>(x_pfc, x_vtx, batch_pfc, batch_vtx,
                                            pfc_w1, pfc_b1, pfc_w2, pfc_b2,
                                            vtx_w1, vtx_b1, vtx_w2, vtx_b2,
                                            pfc_enc, n_pfc, vtx_enc, n_vtx,
                                            pfc_encT, vtx_encT,
                                            goff_pfc, goff_vtx);

    fused_conv_mlp_kernel<<<2048, 128, 0, stream>>>(
        pfc_enc, pfc_encT, n_pfc, vtx_enc, vtx_encT, n_vtx,
        batch_pfc, goff_pfc, goff_vtx, conv_w, conv_b,
        out_w1, out_b1, out_w2, out_b2, out_w3, out_b3, out_w4, out_b4,
        (float*)d_out, N_PFC);
}

// Round 18
// 164.852 us; speedup vs baseline: 1.4418x; 1.0458x over previous
//
#include <hip/hip_runtime.h>
#include <hip/hip_bf16.h>

#define LRELU(val) ((val) >= 0.0f ? (val) : 0.01f * (val))

__device__ __forceinline__ float dot4(float4 a, float4 b, float acc) {
    return fmaf(a.x, b.x, fmaf(a.y, b.y, fmaf(a.z, b.z, fmaf(a.w, b.w, acc))));
}

__device__ __forceinline__ float wdot4(const float* __restrict__ wbase, int c, int q,
                                       float4 a, float acc) {
    acc = fmaf(a.x, wbase[(4 * q + 0) * 32 + c], acc);
    acc = fmaf(a.y, wbase[(4 * q + 1) * 32 + c], acc);
    acc = fmaf(a.z, wbase[(4 * q + 2) * 32 + c], acc);
    acc = fmaf(a.w, wbase[(4 * q + 3) * 32 + c], acc);
    return acc;
}

__device__ inline int lower_bound_i(const int* __restrict__ a, int n, int v) {
    int lo = 0, hi = n;
    while (lo < hi) {
        int m = (lo + hi) >> 1;
        if (a[m] < v) lo = m + 1; else hi = m;
    }
    return lo;
}

// Sortable 32-bit distance key from the QUAD-MAJOR transposed array:
// srcT4[q*Ns + j] = float4 of dims 4q..4q+3 of node j. Lane L reads node
// j = start+L+64s -> consecutive lanes, 16B stride = 16 lines/instr AND only
// 8 dwordx4 issues (R17's fully-scalar transpose needed 32 dword issues for
// the same line count). dot accumulation = R12's dot4 order (validated).
__device__ __forceinline__ unsigned slot_key_T4(
    int s, int lane, int start, int len, int Ns,
    const float4* __restrict__ srcT4, const float* __restrict__ srcn, float ni,
    float4 x0, float4 x1, float4 x2, float4 x3,
    float4 x4, float4 x5, float4 x6, float4 x7)
{
    const int o = lane + 64 * s;
    const bool valid = o < len;
    const int j = valid ? (start + o) : min(start, Ns - 1);
    float dot = 0.0f;
    dot = dot4(srcT4[0 * Ns + j], x0, dot);
    dot = dot4(srcT4[1 * Ns + j], x1, dot);
    dot = dot4(srcT4[2 * Ns + j], x2, dot);
    dot = dot4(srcT4[3 * Ns + j], x3, dot);
    dot = dot4(srcT4[4 * Ns + j], x4, dot);
    dot = dot4(srcT4[5 * Ns + j], x5, dot);
    dot = dot4(srcT4[6 * Ns + j], x6, dot);
    dot = dot4(srcT4[7 * Ns + j], x7, dot);
    const float d2 = (ni + srcn[j]) - 2.0f * dot;   // reference distance formula
    unsigned u = __float_as_uint(d2);
    u = (d2 < 0.0f) ? ~u : (u | 0x80000000u);       // monotone float->uint map
    return valid ? u : 0xFFFFFFFFu;
}

// Membership + compaction for one node (exact lax.top_k tie semantics).
template <int NSL>
__device__ __forceinline__ void select_compact(
    unsigned k0, unsigned k1, unsigned k2, unsigned k3, unsigned k4, unsigned k5,
    unsigned T, int start, int Ns, int* __restrict__ widxW, int lane)
{
    const unsigned long long below = (1ull << lane) - 1ull;
    int m = __popcll(__ballot(k0 < T));
    if (NSL > 1) m += __popcll(__ballot(k1 < T));
    if (NSL > 2) m += __popcll(__ballot(k2 < T));
    if (NSL > 3) m += __popcll(__ballot(k3 < T));
    if (NSL > 4) m += __popcll(__ballot(k4 < T));
    if (NSL > 5) m += __popcll(__ballot(k5 < T));
    const int need = 16 - m;
    const unsigned long long e0 = __ballot(k0 == T);
    const unsigned long long e1 = (NSL > 1) ? __ballot(k1 == T) : 0ull;
    const unsigned long long e2 = (NSL > 2) ? __ballot(k2 == T) : 0ull;
    const unsigned long long e3 = (NSL > 3) ? __ballot(k3 == T) : 0ull;
    const unsigned long long e4 = (NSL > 4) ? __ballot(k4 == T) : 0ull;
    const int eq0 = __popcll(e0), eq1 = eq0 + __popcll(e1), eq2 = eq1 + __popcll(e2),
              eq3 = eq2 + __popcll(e3), eq4 = eq3 + __popcll(e4);
    const bool sel0 = (k0 < T) || ((k0 == T) && (__popcll(e0 & below) < need));
    const bool sel1 = (NSL > 1) && ((k1 < T) || ((k1 == T) && (eq0 + __popcll(e1 & below) < need)));
    const bool sel2 = (NSL > 2) && ((k2 < T) || ((k2 == T) && (eq1 + __popcll(e2 & below) < need)));
    const bool sel3 = (NSL > 3) && ((k3 < T) || ((k3 == T) && (eq2 + __popcll(e3 & below) < need)));
    const bool sel4 = (NSL > 4) && ((k4 < T) || ((k4 == T) && (eq3 + __popcll(e4 & below) < need)));
    const bool sel5 = (NSL > 5) && ((k5 < T) || ((k5 == T) && (eq4 + __popcll(__ballot(k5 == T) & below) < need)));
    const unsigned long long s0 = __ballot(sel0);
    const unsigned long long s1 = __ballot(sel1);
    const unsigned long long s2 = __ballot(sel2);
    const unsigned long long s3 = __ballot(sel3);
    const unsigned long long s4 = __ballot(sel4);
    const unsigned long long s5 = __ballot(sel5);
    const int c0 = __popcll(s0), c1 = c0 + __popcll(s1), c2 = c1 + __popcll(s2),
              c3 = c2 + __popcll(s3), c4 = c3 + __popcll(s4);
    if (lane < 16) widxW[lane] = min(start, Ns - 1);   // fallback, len<16 never in practice
    __builtin_amdgcn_wave_barrier();
    if (sel0) widxW[__popcll(s0 & below)] = start + lane;
    if (NSL > 1 && sel1) widxW[c0 + __popcll(s1 & below)] = start + lane + 64;
    if (NSL > 2 && sel2) widxW[c1 + __popcll(s2 & below)] = start + lane + 128;
    if (NSL > 3 && sel3) widxW[c2 + __popcll(s3 & below)] = start + lane + 192;
    if (NSL > 4 && sel4) widxW[c3 + __popcll(s4 & below)] = start + lane + 256;
    if (NSL > 5 && sel5) widxW[c4 + __popcll(s5 & below)] = start + lane + 320;
    __builtin_amdgcn_wave_barrier();
}

// ---------------------------------------------------------------------------
// TWO independent nodes per wave, all phases interleaved. Distances from the
// quad-major transposed array (coalesced, vector loads); neighbor rows from
// the row-major array. Ballot bisection (lo seeded at 0x80000000 — all valid
// keys have bit31 set) + exact tie-order compaction. No block barriers.
// ---------------------------------------------------------------------------
template <int NSL>
__device__ __forceinline__ void conv_pair(
    float4 ax0, float4 ax1, float4 ax2, float4 ax3,
    float4 ax4, float4 ax5, float4 ax6, float4 ax7,
    float niA, int startA, int lenA,
    float4 bx0, float4 bx1, float4 bx2, float4 bx3,
    float4 bx4, float4 bx5, float4 bx6, float4 bx7,
    float niB, int startB, int lenB,
    const float* __restrict__ srcf, const float4* __restrict__ srcT4,
    const float* __restrict__ srcn, int Ns,
    const float* __restrict__ W, const float* __restrict__ Bc,
    float4 w20, float4 w21, float4 w22, float4 w23,
    float4 w24, float4 w25, float4 w26, float4 w27,
    float4* __restrict__ sNbrA, float4* __restrict__ sNbrB,
    int* __restrict__ widxA, int* __restrict__ widxB,
    int lane, float& vOutA, float& vOutB)
{
    unsigned kA0 = 0xFFFFFFFFu, kA1 = 0xFFFFFFFFu, kA2 = 0xFFFFFFFFu,
             kA3 = 0xFFFFFFFFu, kA4 = 0xFFFFFFFFu, kA5 = 0xFFFFFFFFu;
    unsigned kB0 = 0xFFFFFFFFu, kB1 = 0xFFFFFFFFu, kB2 = 0xFFFFFFFFu,
             kB3 = 0xFFFFFFFFu, kB4 = 0xFFFFFFFFu, kB5 = 0xFFFFFFFFu;
    kA0 = slot_key_T4(0, lane, startA, lenA, Ns, srcT4, srcn, niA, ax0, ax1, ax2, ax3, ax4, ax5, ax6, ax7);
    kB0 = slot_key_T4(0, lane, startB, lenB, Ns, srcT4, srcn, niB, bx0, bx1, bx2, bx3, bx4, bx5, bx6, bx7);
    if (NSL > 1) {
        if (lenA > 64)  kA1 = slot_key_T4(1, lane, startA, lenA, Ns, srcT4, srcn, niA, ax0, ax1, ax2, ax3, ax4, ax5, ax6, ax7);
        if (lenB > 64)  kB1 = slot_key_T4(1, lane, startB, lenB, Ns, srcT4, srcn, niB, bx0, bx1, bx2, bx3, bx4, bx5, bx6, bx7);
    }
    if (NSL > 2) {
        if (lenA > 128) kA2 = slot_key_T4(2, lane, startA, lenA, Ns, srcT4, srcn, niA, ax0, ax1, ax2, ax3, ax4, ax5, ax6, ax7);
        if (lenB > 128) kB2 = slot_key_T4(2, lane, startB, lenB, Ns, srcT4, srcn, niB, bx0, bx1, bx2, bx3, bx4, bx5, bx6, bx7);
    }
    if (NSL > 3) {
        if (lenA > 192) kA3 = slot_key_T4(3, lane, startA, lenA, Ns, srcT4, srcn, niA, ax0, ax1, ax2, ax3, ax4, ax5, ax6, ax7);
        if (lenB > 192) kB3 = slot_key_T4(3, lane, startB, lenB, Ns, srcT4, srcn, niB, bx0, bx1, bx2, bx3, bx4, bx5, bx6, bx7);
    }
    if (NSL > 4) {
        if (lenA > 256) kA4 = slot_key_T4(4, lane, startA, lenA, Ns, srcT4, srcn, niA, ax0, ax1, ax2, ax3, ax4, ax5, ax6, ax7);
        if (lenB > 256) kB4 = slot_key_T4(4, lane, startB, lenB, Ns, srcT4, srcn, niB, bx0, bx1, bx2, bx3, bx4, bx5, bx6, bx7);
    }
    if (NSL > 5) {
        if (lenA > 320) kA5 = slot_key_T4(5, lane, startA, lenA, Ns, srcT4, srcn, niA, ax0, ax1, ax2, ax3, ax4, ax5, ax6, ax7);
        if (lenB > 320) kB5 = slot_key_T4(5, lane, startB, lenB, Ns, srcT4, srcn, niB, bx0, bx1, bx2, bx3, bx4, bx5, bx6, bx7);
    }

    unsigned loA = 0x80000000u, hiA = 0xFFFFFFFFu, loB = 0x80000000u, hiB = 0xFFFFFFFFu;
#pragma unroll 1
    for (int it = 0; it < 31; ++it) {
        const unsigned mA = loA + ((hiA - loA) >> 1);
        const unsigned mB = loB + ((hiB - loB) >> 1);
        int cA = __popcll(__ballot(kA0 <= mA));
        int cB = __popcll(__ballot(kB0 <= mB));
        if (NSL > 1) { cA += __popcll(__ballot(kA1 <= mA)); cB += __popcll(__ballot(kB1 <= mB)); }
        if (NSL > 2) { cA += __popcll(__ballot(kA2 <= mA)); cB += __popcll(__ballot(kB2 <= mB)); }
        if (NSL > 3) { cA += __popcll(__ballot(kA3 <= mA)); cB += __popcll(__ballot(kB3 <= mB)); }
        if (NSL > 4) { cA += __popcll(__ballot(kA4 <= mA)); cB += __popcll(__ballot(kB4 <= mB)); }
        if (NSL > 5) { cA += __popcll(__ballot(kA5 <= mA)); cB += __popcll(__ballot(kB5 <= mB)); }
        if (loA != hiA) { if (cA >= 16) hiA = mA; else loA = mA + 1; }
        if (loB != hiB) { if (cB >= 16) hiB = mB; else loB = mB + 1; }
        if (loA == hiA && loB == hiB) break;
    }

    select_compact<NSL>(kA0, kA1, kA2, kA3, kA4, kA5, loA, startA, Ns, widxA, lane);
    select_compact<NSL>(kB0, kB1, kB2, kB3, kB4, kB5, loB, startB, Ns, widxB, lane);

    const int c = lane & 31;
    const int n0 = lane >> 3, qq = lane & 7;
    const int n1 = n0 + 8;
    int jA0 = widxA[n0]; jA0 = ((unsigned)jA0 < (unsigned)Ns) ? jA0 : 0;
    int jA1 = widxA[n1]; jA1 = ((unsigned)jA1 < (unsigned)Ns) ? jA1 : 0;
    int jB0 = widxB[n0]; jB0 = ((unsigned)jB0 < (unsigned)Ns) ? jB0 : 0;
    int jB1 = widxB[n1]; jB1 = ((unsigned)jB1 < (unsigned)Ns) ? jB1 : 0;
    const float4* S = reinterpret_cast<const float4*>(srcf);
    const float4 rA0 = S[(size_t)jA0 * 8 + qq];
    const float4 rA1 = S[(size_t)jA1 * 8 + qq];
    const float4 rB0 = S[(size_t)jB0 * 8 + qq];
    const float4 rB1 = S[(size_t)jB1 * 8 + qq];

    float baseA = Bc[c];
    baseA = wdot4(W, c, 0, ax0, baseA); baseA = wdot4(W, c, 1, ax1, baseA);
    baseA = wdot4(W, c, 2, ax2, baseA); baseA = wdot4(W, c, 3, ax3, baseA);
    baseA = wdot4(W, c, 4, ax4, baseA); baseA = wdot4(W, c, 5, ax5, baseA);
    baseA = wdot4(W, c, 6, ax6, baseA); baseA = wdot4(W, c, 7, ax7, baseA);
    float dA = 0.0f;
    dA = dot4(ax0, w20, dA); dA = dot4(ax1, w21, dA); dA = dot4(ax2, w22, dA); dA = dot4(ax3, w23, dA);
    dA = dot4(ax4, w24, dA); dA = dot4(ax5, w25, dA); dA = dot4(ax6, w26, dA); dA = dot4(ax7, w27, dA);
    const float cbaseA = baseA - dA;

    float baseB = Bc[c];
    baseB = wdot4(W, c, 0, bx0, baseB); baseB = wdot4(W, c, 1, bx1, baseB);
    baseB = wdot4(W, c, 2, bx2, baseB); baseB = wdot4(W, c, 3, bx3, baseB);
    baseB = wdot4(W, c, 4, bx4, baseB); baseB = wdot4(W, c, 5, bx5, baseB);
    baseB = wdot4(W, c, 6, bx6, baseB); baseB = wdot4(W, c, 7, bx7, baseB);
    float dB = 0.0f;
    dB = dot4(bx0, w20, dB); dB = dot4(bx1, w21, dB); dB = dot4(bx2, w22, dB); dB = dot4(bx3, w23, dB);
    dB = dot4(bx4, w24, dB); dB = dot4(bx5, w25, dB); dB = dot4(bx6, w26, dB); dB = dot4(bx7, w27, dB);
    const float cbaseB = baseB - dB;

    sNbrA[n0 * 8 + qq] = rA0;
    sNbrA[n1 * 8 + qq] = rA1;
    sNbrB[n0 * 8 + qq] = rB0;
    sNbrB[n1 * 8 + qq] = rB1;
    __builtin_amdgcn_wave_barrier();

    const int half = lane >> 5;
    float vmA = -__builtin_huge_valf(), vmB = -__builtin_huge_valf();
#pragma unroll 1
    for (int r = 0; r < 8; ++r) {
        const float4* nA = sNbrA + (2 * r + half) * 8;
        const float4* nB = sNbrB + (2 * r + half) * 8;
        float accA = cbaseA, accB = cbaseB;
        accA = dot4(nA[0], w20, accA); accB = dot4(nB[0], w20, accB);
        accA = dot4(nA[1], w21, accA); accB = dot4(nB[1], w21, accB);
        accA = dot4(nA[2], w22, accA); accB = dot4(nB[2], w22, accB);
        accA = dot4(nA[3], w23, accA); accB = dot4(nB[3], w23, accB);
        accA = dot4(nA[4], w24, accA); accB = dot4(nB[4], w24, accB);
        accA = dot4(nA[5], w25, accA); accB = dot4(nB[5], w25, accB);
        accA = dot4(nA[6], w26, accA); accB = dot4(nB[6], w26, accB);
        accA = dot4(nA[7], w27, accA); accB = dot4(nB[7], w27, accB);
        vmA = fmaxf(vmA, LRELU(accA));
        vmB = fmaxf(vmB, LRELU(accB));
    }
    vmA = fmaxf(vmA, __shfl_xor(vmA, 32));
    vmB = fmaxf(vmB, __shfl_xor(vmB, 32));
    vOutA = vmA;
    vOutB = vmB;
}

// ---------------------------------------------------------------------------
// Kernel 1: both MLP2 encoders + sq norms + group-offset tables + quad-major
// transposed feature copies (encT4[q*Nn + node] = float4 of dims 4q..4q+3).
// ---------------------------------------------------------------------------
__launch_bounds__(256)
__global__ void encode_kernel(const float* __restrict__ x_pfc, const float* __restrict__ x_vtx,
                              const int* __restrict__ bpfc, const int* __restrict__ bvtx,
                              const float* __restrict__ pw1, const float* __restrict__ pb1,
                              const float* __restrict__ pw2, const float* __restrict__ pb2,
                              const float* __restrict__ vw1, const float* __restrict__ vb1,
                              const float* __restrict__ vw2, const float* __restrict__ vb2,
                              float* __restrict__ pfc_enc, float* __restrict__ pfc_norm,
                              float* __restrict__ vtx_enc, float* __restrict__ vtx_norm,
                              float* __restrict__ pfc_encT4, float* __restrict__ vtx_encT4,
                              int* __restrict__ goff_pfc, int* __restrict__ goff_vtx) {
    __shared__ float h1s[8][32];
    const int t = threadIdx.x;
    const int c = t & 31;
    const int nl = t >> 5;

    if (blockIdx.x == 0) {
        if (t < 33) goff_pfc[t] = lower_bound_i(bpfc, 8192, t);
        else if (t >= 64 && t < 97) goff_vtx[t - 64] = lower_bound_i(bvtx, 2048, t - 64);
    }

    const bool is_pfc = (blockIdx.x < 1024);
    const int node = (is_pfc ? blockIdx.x : (blockIdx.x - 1024)) * 8 + nl;
    const int din = is_pfc ? 7 : 4;
    const int Nn = is_pfc ? 8192 : 2048;
    const float* __restrict__ xin = is_pfc ? (x_pfc + node * 7) : (x_vtx + node * 4);
    const float* __restrict__ w1 = is_pfc ? pw1 : vw1;
    const float* __restrict__ b1 = is_pfc ? pb1 : vb1;
    const float* __restrict__ w2 = is_pfc ? pw2 : vw2;
    const float* __restrict__ b2 = is_pfc ? pb2 : vb2;
    float* __restrict__ enc   = is_pfc ? pfc_enc : vtx_enc;
    float* __restrict__ encT4 = is_pfc ? pfc_encT4 : vtx_encT4;
    float* __restrict__ nrm   = is_pfc ? pfc_norm : vtx_norm;

    float h1 = b1[c];
    for (int d = 0; d < din; ++d) h1 = fmaf(xin[d], w1[d * 32 + c], h1);
    h1 = LRELU(h1);
    h1s[nl][c] = h1;
    __syncthreads();

    float h2 = b2[c];
#pragma unroll
    for (int d = 0; d < 32; ++d) h2 = fmaf(h1s[nl][d], w2[d * 32 + c], h2);
    h2 = LRELU(h2);
    enc[node * 32 + c] = h2;
    // quad-major transpose: dim c -> quad c>>2, elem c&3
    encT4[((size_t)(c >> 2) * Nn + node) * 4 + (c & 3)] = h2;

    float s = h2 * h2;
#pragma unroll
    for (int m = 16; m >= 1; m >>= 1) s += __shfl_xor(s, m);
    if (c == 0) nrm[node] = s;
}

// ---------------------------------------------------------------------------
// Kernel 2: fused conv1 + conv2 + output MLP. TWO nodes per wave, 128-thr
// blocks, ZERO block barriers. MLP weights read straight from GLOBAL in the
// tail (L2-hot column reads; wave-uniform reads -> s_load). LDS ~10KB keeps
// residency at the VGPR cap (4 waves/SIMD).
// ---------------------------------------------------------------------------
__launch_bounds__(128)
__global__ void fused_conv_mlp_kernel(
    const float* __restrict__ pfc_enc, const float4* __restrict__ pfc_encT4,
    const float* __restrict__ n_pfc,
    const float* __restrict__ vtx_enc, const float4* __restrict__ vtx_encT4,
    const float* __restrict__ n_vtx,
    const int* __restrict__ bpfc,
    const int* __restrict__ goff_pfc, const int* __restrict__ goff_vtx,
    const float* __restrict__ W, const float* __restrict__ Bc,
    const float* __restrict__ ow1, const float* __restrict__ ob1,
    const float* __restrict__ ow2, const float* __restrict__ ob2,
    const float* __restrict__ ow3, const float* __restrict__ ob3,
    const float* __restrict__ ow4, const float* __restrict__ ob4,
    float* __restrict__ dout, int N)
{
    __shared__ __align__(16) float4 sNbr[2][2][128];   // [wave][node]
    __shared__ int widx[2][2][16];
    __shared__ __align__(16) float sRow[2][2][32];
    __shared__ float sEx1[2][2][64];

    const int t = threadIdx.x;
    const int lane = t & 63;
    const int w = t >> 6;
    const int b = blockIdx.x;              // 2048 blocks x 4 nodes
    const int xcd = b & 7, chunk = b >> 3;
    const int iA = xcd * 1024 + chunk * 4 + w * 2;
    const int iB = iA + 1;
    const int c = lane & 31;

    // W2 column (rows 32..63, col c) into 8 float4 regs (L2-hot broadcast)
    const float4 w20 = make_float4(W[32 * 32 + c], W[33 * 32 + c], W[34 * 32 + c], W[35 * 32 + c]);
    const float4 w21 = make_float4(W[36 * 32 + c], W[37 * 32 + c], W[38 * 32 + c], W[39 * 32 + c]);
    const float4 w22 = make_float4(W[40 * 32 + c], W[41 * 32 + c], W[42 * 32 + c], W[43 * 32 + c]);
    const float4 w23 = make_float4(W[44 * 32 + c], W[45 * 32 + c], W[46 * 32 + c], W[47 * 32 + c]);
    const float4 w24 = make_float4(W[48 * 32 + c], W[49 * 32 + c], W[50 * 32 + c], W[51 * 32 + c]);
    const float4 w25 = make_float4(W[52 * 32 + c], W[53 * 32 + c], W[54 * 32 + c], W[55 * 32 + c]);
    const float4 w26 = make_float4(W[56 * 32 + c], W[57 * 32 + c], W[58 * 32 + c], W[59 * 32 + c]);
    const float4 w27 = make_float4(W[60 * 32 + c], W[61 * 32 + c], W[62 * 32 + c], W[63 * 32 + c]);

    float4* sNbrA = &sNbr[w][0][0];
    float4* sNbrB = &sNbr[w][1][0];
    int* widxA = &widx[w][0][0];
    int* widxB = &widx[w][1][0];

    const int gA = bpfc[iA], gB = bpfc[iB];

    // ---- conv1: src = dst = pfc ----
    const float4* xA = reinterpret_cast<const float4*>(pfc_enc + (size_t)iA * 32);
    const float4 a0 = xA[0], a1 = xA[1], a2 = xA[2], a3 = xA[3],
                 a4 = xA[4], a5 = xA[5], a6 = xA[6], a7 = xA[7];
    const float4* xB = reinterpret_cast<const float4*>(pfc_enc + (size_t)iB * 32);
    const float4 b0 = xB[0], b1 = xB[1], b2 = xB[2], b3 = xB[3],
                 b4 = xB[4], b5 = xB[5], b6 = xB[6], b7 = xB[7];
    const float niA = n_pfc[iA], niB = n_pfc[iB];
    const int s1A = goff_pfc[gA], len1A = min(goff_pfc[gA + 1] - s1A, 384);
    const int s1B = goff_pfc[gB], len1B = min(goff_pfc[gB + 1] - s1B, 384);

    float v1A, v1B;
    {
        const int nsl = (max(len1A, len1B) + 63) >> 6;
        if (nsl <= 4)
            conv_pair<4>(a0, a1, a2, a3, a4, a5, a6, a7, niA, s1A, len1A,
                         b0, b1, b2, b3, b4, b5, b6, b7, niB, s1B, len1B,
                         pfc_enc, pfc_encT4, n_pfc, 8192, W, Bc,
                         w20, w21, w22, w23, w24, w25, w26, w27,
                         sNbrA, sNbrB, widxA, widxB, lane, v1A, v1B);
        else
            conv_pair<6>(a0, a1, a2, a3, a4, a5, a6, a7, niA, s1A, len1A,
                         b0, b1, b2, b3, b4, b5, b6, b7, niB, s1B, len1B,
                         pfc_enc, pfc_encT4, n_pfc, 8192, W, Bc,
                         w20, w21, w22, w23, w24, w25, w26, w27,
                         sNbrA, sNbrB, widxA, widxB, lane, v1A, v1B);
    }

    if (lane < 32) { sRow[w][0][lane] = v1A; sRow[w][1][lane] = v1B; }
    float nfA = v1A * v1A, nfB = v1B * v1B;
#pragma unroll
    for (int m = 16; m >= 1; m >>= 1) { nfA += __shfl_xor(nfA, m); nfB += __shfl_xor(nfB, m); }
    __builtin_amdgcn_wave_barrier();

    // ---- conv2: dst = feats1 rows (wave-private LDS), src = vtx ----
    const float4* fA = reinterpret_cast<const float4*>(&sRow[w][0][0]);
    const float4 ya0 = fA[0], ya1 = fA[1], ya2 = fA[2], ya3 = fA[3],
                 ya4 = fA[4], ya5 = fA[5], ya6 = fA[6], ya7 = fA[7];
    const float4* fB = reinterpret_cast<const float4*>(&sRow[w][1][0]);
    const float4 yb0 = fB[0], yb1 = fB[1], yb2 = fB[2], yb3 = fB[3],
                 yb4 = fB[4], yb5 = fB[5], yb6 = fB[6], yb7 = fB[7];
    const int s2A = goff_vtx[gA], len2A = min(goff_vtx[gA + 1] - s2A, 128);
    const int s2B = goff_vtx[gB], len2B = min(goff_vtx[gB + 1] - s2B, 128);

    float v2A, v2B;
    conv_pair<2>(ya0, ya1, ya2, ya3, ya4, ya5, ya6, ya7, nfA, s2A, len2A,
                 yb0, yb1, yb2, yb3, yb4, yb5, yb6, yb7, nfB, s2B, len2B,
                 vtx_enc, vtx_encT4, n_vtx, 2048, W, Bc,
                 w20, w21, w22, w23, w24, w25, w26, w27,
                 sNbrA, sNbrB, widxA, widxB, lane, v2A, v2B);

    // ---- output MLP 32 -> 64 -> 32 -> 4 -> 1 (lrelu each), wave-private ----
    if (lane < 32) { sRow[w][0][lane] = v2A; sRow[w][1][lane] = v2B; }
    __builtin_amdgcn_wave_barrier();

    // layer 1: 64 outputs per node, one per lane (weights from global, L2-hot)
    {
        float h1a = ob1[lane], h1b = h1a;
#pragma unroll
        for (int d = 0; d < 32; ++d) {
            const float wv = ow1[d * 64 + lane];
            h1a = fmaf(sRow[w][0][d], wv, h1a);
            h1b = fmaf(sRow[w][1][d], wv, h1b);
        }
        sEx1[w][0][lane] = LRELU(h1a);
        sEx1[w][1][lane] = LRELU(h1b);
    }
    __builtin_amdgcn_wave_barrier();

    // layer 2: 32 outputs per node (both halves duplicate)
    {
        float h2a = ob2[c], h2b = h2a;
#pragma unroll
        for (int d = 0; d < 64; ++d) {
            const float wv = ow2[d * 32 + c];
            h2a = fmaf(sEx1[w][0][d], wv, h2a);
            h2b = fmaf(sEx1[w][1][d], wv, h2b);
        }
        if (lane < 32) { sRow[w][0][lane] = LRELU(h2a); sRow[w][1][lane] = LRELU(h2b); }
    }
    __builtin_amdgcn_wave_barrier();

    // layers 3+4 (tiny): wave-uniform weight reads -> scalar loads
    {
        float aa0 = ob3[0], aa1 = ob3[1], aa2 = ob3[2], aa3 = ob3[3];
        float bb0 = aa0, bb1 = aa1, bb2 = aa2, bb3 = aa3;
#pragma unroll
        for (int d = 0; d < 32; ++d) {
            const float ea = sRow[w][0][d], eb = sRow[w][1][d];
            const float w0v = ow3[d * 4 + 0], w1v = ow3[d * 4 + 1],
                        w2v = ow3[d * 4 + 2], w3v = ow3[d * 4 + 3];
            aa0 = fmaf(ea, w0v, aa0); bb0 = fmaf(eb, w0v, bb0);
            aa1 = fmaf(ea, w1v, aa1); bb1 = fmaf(eb, w1v, bb1);
            aa2 = fmaf(ea, w2v, aa2); bb2 = fmaf(eb, w2v, bb2);
            aa3 = fmaf(ea, w3v, aa3); bb3 = fmaf(eb, w3v, bb3);
        }
        aa0 = LRELU(aa0); aa1 = LRELU(aa1); aa2 = LRELU(aa2); aa3 = LRELU(aa3);
        bb0 = LRELU(bb0); bb1 = LRELU(bb1); bb2 = LRELU(bb2); bb3 = LRELU(bb3);
        const float q0 = ow4[0], q1 = ow4[1], q2 = ow4[2], q3 = ow4[3], bz = ob4[0];
        float oA = bz, oB = bz;
        oA = fmaf(aa0, q0, oA); oA = fmaf(aa1, q1, oA); oA = fmaf(aa2, q2, oA); oA = fmaf(aa3, q3, oA);
        oB = fmaf(bb0, q0, oB); oB = fmaf(bb1, q1, oB); oB = fmaf(bb2, q2, oB); oB = fmaf(bb3, q3, oB);
        oA = LRELU(oA); oB = LRELU(oB);

        if (lane == 0) { dout[iA] = oA; dout[iB] = oB; }              // output 0
        if (lane == 1) { dout[N + iA] = (float)gA; dout[N + iB] = (float)gB; }  // output 1
    }
}

// ---------------------------------------------------------------------------
extern "C" void kernel_launch(void* const* d_in, const int* in_sizes, int n_in,
                              void* d_out, int out_size, void* d_ws, size_t ws_size,
                              hipStream_t stream) {
    const float* x_pfc     = (const float*)d_in[0];
    const float* x_vtx     = (const float*)d_in[1];
    const int*   batch_pfc = (const int*)d_in[2];
    const int*   batch_vtx = (const int*)d_in[3];
    const float* pfc_w1 = (const float*)d_in[4];
    const float* pfc_b1 = (const float*)d_in[5];
    const float* pfc_w2 = (const float*)d_in[6];
    const float* pfc_b2 = (const float*)d_in[7];
    const float* vtx_w1 = (const float*)d_in[8];
    const float* vtx_b1 = (const float*)d_in[9];
    const float* vtx_w2 = (const float*)d_in[10];
    const float* vtx_b2 = (const float*)d_in[11];
    const float* conv_w = (const float*)d_in[12];
    const float* conv_b = (const float*)d_in[13];
    const float* out_w1 = (const float*)d_in[14];
    const float* out_b1 = (const float*)d_in[15];
    const float* out_w2 = (const float*)d_in[16];
    const float* out_b2 = (const float*)d_in[17];
    const float* out_w3 = (const float*)d_in[18];
    const float* out_b3 = (const float*)d_in[19];
    const float* out_w4 = (const float*)d_in[20];
    const float* out_b4 = (const float*)d_in[21];

    const int N_PFC = 8192;

    float* ws = (float*)d_ws;
    float* pfc_enc   = ws;                     // 8192*32
    float* vtx_enc   = ws + 262144;            // 2048*32
    float* n_pfc     = ws + 327680;            // 8192
    float* n_vtx     = ws + 335872;            // 2048
    int*   goff_pfc  = (int*)(ws + 337920);    // 33 (+pad)
    int*   goff_vtx  = (int*)(ws + 337984);    // 33 (+pad)
    float* pfc_encT4 = ws + 338048;            // 8 quads * 8192 * 4 = 262144 (16B-aligned: offset mult of 4)
    float* vtx_encT4 = ws + 600192;            // 8 * 2048 * 4 = 65536  (total 665728 floats)

    encode_kernel<<<1280, 256, 0, stream>>>(x_pfc, x_vtx, batch_pfc, batch_vtx,
                                            pfc_w1, pfc_b1, pfc_w2, pfc_b2,
                                            vtx_w1, vtx_b1, vtx_w2, vtx_b2,
                                            pfc_enc, n_pfc, vtx_enc, n_vtx,
                                            pfc_encT4, vtx_encT4,
                                            goff_pfc, goff_vtx);

    fused_conv_mlp_kernel<<<2048, 128, 0, stream>>>(
        pfc_enc, (const float4*)pfc_encT4, n_pfc,
        vtx_enc, (const float4*)vtx_encT4, n_vtx,
        batch_pfc, goff_pfc, goff_vtx, conv_w, conv_b,
        out_w1, out_b1, out_w2, out_b2, out_w3, out_b3, out_w4, out_b4,
        (float*)d_out, N_PFC);
}